// Round 9
// baseline (2168.436 us; speedup 1.0000x reference)
//
#include <hip/hip_runtime.h>

typedef __bf16 bf16;
typedef __bf16 bf16x4 __attribute__((ext_vector_type(4)));
typedef __bf16 bf16x8 __attribute__((ext_vector_type(8)));
typedef float f32x4 __attribute__((ext_vector_type(4)));
typedef short short4v __attribute__((ext_vector_type(4)));

__device__ __forceinline__ short f2bs(float x) {
  bf16 hv = (bf16)x;
  return __builtin_bit_cast(short, hv);
}

__device__ __forceinline__ void gl_lds16(const void* g, void* l) {
  __builtin_amdgcn_global_load_lds(
      (const __attribute__((address_space(1))) unsigned int*)g,
      (__attribute__((address_space(3))) unsigned int*)l, 16, 0, 0);
}

// ---------------------------------------------------------------------------
// Weight transpose+convert: fp32 [K][N] -> bf16 [N][K]; 64k x 32n tile.
// ---------------------------------------------------------------------------
__global__ __launch_bounds__(256) void wt_k(const float* __restrict__ in,
    bf16* __restrict__ out, int K, int N, long in_ls, long out_ls)
{
  __shared__ float t[64][33];
  const int z = blockIdx.z;
  const float* ip = in + (size_t)z * in_ls;
  bf16* op = out + (size_t)z * out_ls;
  const int n0 = blockIdx.x * 32, k0 = blockIdx.y * 64;
  const int tid = threadIdx.x;
  const int kr = tid >> 3, nc = (tid & 7) * 4;
#pragma unroll
  for (int hh = 0; hh < 2; ++hh) {
    float4 v = *(const float4*)(ip + (size_t)(k0 + kr + hh * 32) * N + n0 + nc);
    t[kr + hh * 32][nc]     = v.x;
    t[kr + hh * 32][nc + 1] = v.y;
    t[kr + hh * 32][nc + 2] = v.z;
    t[kr + hh * 32][nc + 3] = v.w;
  }
  __syncthreads();
  const int nr = tid >> 3, kc = (tid & 7) * 8;
  bf16x8 o;
#pragma unroll
  for (int j = 0; j < 8; ++j) o[j] = (bf16)t[kc + j][nr];
  *(bf16x8*)(op + (size_t)(n0 + nr) * K + k0 + kc) = o;
}

// Merged square-weight pre-pass: z -> {Wq,Wk,Wv,Wo} x layer (1024x1024 each)
__global__ __launch_bounds__(256) void wt4_k(const float* __restrict__ Wq,
    const float* __restrict__ Wk, const float* __restrict__ Wv,
    const float* __restrict__ Wo, bf16* __restrict__ Bqkv,
    bf16* __restrict__ Bo)
{
  __shared__ float t[64][33];
  const int z = blockIdx.z;
  const int which = z >> 3, layer = z & 7;
  const long M1 = 1024 * 1024, M3 = 3 * M1;
  const float* ip = (which == 0 ? Wq : which == 1 ? Wk : which == 2 ? Wv : Wo)
                    + (size_t)layer * M1;
  bf16* op = (which < 3) ? (Bqkv + (size_t)layer * M3 + (size_t)which * M1)
                         : (Bo + (size_t)layer * M1);
  const int n0 = blockIdx.x * 32, k0 = blockIdx.y * 64;
  const int tid = threadIdx.x;
  const int kr = tid >> 3, nc = (tid & 7) * 4;
#pragma unroll
  for (int hh = 0; hh < 2; ++hh) {
    float4 v = *(const float4*)(ip + (size_t)(k0 + kr + hh * 32) * 1024 + n0 + nc);
    t[kr + hh * 32][nc]     = v.x;
    t[kr + hh * 32][nc + 1] = v.y;
    t[kr + hh * 32][nc + 2] = v.z;
    t[kr + hh * 32][nc + 3] = v.w;
  }
  __syncthreads();
  const int nr = tid >> 3, kc = (tid & 7) * 8;
  bf16x8 o;
#pragma unroll
  for (int j = 0; j < 8; ++j) o[j] = (bf16)t[kc + j][nr];
  *(bf16x8*)(op + (size_t)(n0 + nr) * 1024 + k0 + kc) = o;
}

// ---------------------------------------------------------------------------
// Embedding: h[m][d] = emb[x[m]][d]*32 + PE(s,d)
// ---------------------------------------------------------------------------
__global__ __launch_bounds__(256) void embed_k(const int* __restrict__ x,
    const float* __restrict__ emb, float* __restrict__ h)
{
  const int m = blockIdx.x, t = threadIdx.x;
  const int s = m & 1023;
  const int tok = x[m];
  const int d0 = t * 4;
  float4 e = *(const float4*)(emb + (size_t)tok * 1024 + d0);
  const float* ep = &e.x;
  float r[4];
#pragma unroll
  for (int j = 0; j < 4; ++j) {
    int d = d0 + j;
    float freq = expf((float)(d & ~1) * (-9.2103403719761836f / 1024.f));
    float ang = (float)s * freq;
    float pe = (d & 1) ? cosf(ang) : sinf(ang);
    r[j] = ep[j] * 32.f + pe;
  }
  *(float4*)(h + (size_t)m * 1024 + d0) = make_float4(r[0], r[1], r[2], r[3]);
}

// ---------------------------------------------------------------------------
// LayerNorm (fp32 in, bf16 out), one block per row of 1024
// ---------------------------------------------------------------------------
__global__ __launch_bounds__(256) void ln_k(const float* __restrict__ h,
    const float* __restrict__ g, const float* __restrict__ b,
    bf16* __restrict__ out)
{
  const int row = blockIdx.x, t = threadIdx.x;
  const float* hr = h + (size_t)row * 1024;
  float4 x = *(const float4*)(hr + t * 4);
  float s  = x.x + x.y + x.z + x.w;
  float ss = x.x * x.x + x.y * x.y + x.z * x.z + x.w * x.w;
#pragma unroll
  for (int off = 32; off >= 1; off >>= 1) {
    s  += __shfl_down(s, off);
    ss += __shfl_down(ss, off);
  }
  __shared__ float sb[4], ssb[4];
  if ((t & 63) == 0) { sb[t >> 6] = s; ssb[t >> 6] = ss; }
  __syncthreads();
  s  = sb[0] + sb[1] + sb[2] + sb[3];
  ss = ssb[0] + ssb[1] + ssb[2] + ssb[3];
  const float mean = s * (1.f / 1024.f);
  const float var  = ss * (1.f / 1024.f) - mean * mean;
  const float rstd = rsqrtf(var + 1e-5f);
  const float* xp = &x.x;
#pragma unroll
  for (int j = 0; j < 4; ++j) {
    int d = t * 4 + j;
    out[(size_t)row * 1024 + d] = (bf16)((xp[j] - mean) * rstd * g[d] + b[d]);
  }
}

// ---------------------------------------------------------------------------
// GEMM 256x256 8-PHASE (proj): C(f32) = A * Bt^T + bias.
// 512 thr / 8 waves (2M x 4N), per-wave 128x64 out (acc 128 VGPR),
// 128 KB dbuf LDS -> 1 block/CU. Per K-tile: 4 phases, each
// { issue quarter-stage(t+1); [p0: vmcnt(2)+barrier]; ds_read subtile;
//   setprio(1) 16 MFMA setprio(0); barrier }.
// Quarter q: q0=A rows 0-127, q1=A 128-255, q2=B 0-127, q3=B 128-255.
// vmcnt(2) at p0 drains tile t's 8 loads, leaves t+1's q0 in flight.
// Operand-swapped MFMA -> coalesced float4 C stores.
// ---------------------------------------------------------------------------
__global__ __launch_bounds__(512) void gemm256p_k(
    const bf16* __restrict__ A, const bf16* __restrict__ Bt,
    const float* __restrict__ bias, float* __restrict__ C,
    int M, int N, int K)
{
  __shared__ __align__(16) bf16 As[2][256 * 64];
  __shared__ __align__(16) bf16 Bs[2][256 * 64];

  const int nwg = gridDim.x;
  const int orig = blockIdx.x;
  const int q8 = nwg >> 3, r8 = nwg & 7;
  const int xcd = orig & 7, loc = orig >> 3;
  const int wg = (xcd < r8 ? xcd * (q8 + 1) : r8 * (q8 + 1) + (xcd - r8) * q8) + loc;
  const int nrowt = M >> 8;
  const int rowt = wg & (nrowt - 1);
  const int colt = wg / nrowt;
  const int m0 = rowt * 256;
  const int n0 = colt * 256;
  const int nt = K >> 6;

  const int tid = threadIdx.x;
  const int lane = tid & 63;
  const int wbase = tid & ~63;
  const int wid = tid >> 6;
  const int wm = wid >> 2;      // 0..1 -> 128-row half
  const int wn = wid & 3;       // 0..3 -> 64-col quarter
  const int qr = lane & 15, grp = lane >> 4;

  f32x4 acc[8][4];
#pragma unroll
  for (int i = 0; i < 8; ++i)
#pragma unroll
    for (int j = 0; j < 4; ++j) acc[i][j] = (f32x4){0.f, 0.f, 0.f, 0.f};

  // quarter-stage: 128 rows x 64 cols bf16 = 16 KB = 1024 chunks, 2/thread
  auto stageQ = [&](int bufi, int kt, int q) {
    const bf16* base = (q < 2) ? A : Bt;
    const int r0 = (q & 1) * 128;
    const int t0 = (q < 2) ? m0 : n0;
    bf16* lds = (q < 2) ? &As[bufi][0] : &Bs[bufi][0];
#pragma unroll
    for (int it = 0; it < 2; ++it) {
      const int idx = it * 512 + tid;
      const int row = idx >> 3, c = idx & 7;
      const int bo = (c * 16) ^ ((row & 7) << 4);
      gl_lds16((const char*)(base + (size_t)(t0 + r0 + row) * K + kt) + bo,
               (char*)lds + (size_t)(r0 * 8 + it * 512 + wbase) * 16);
    }
  };

  // prologue: tile 0 fully staged
  stageQ(0, 0, 0); stageQ(0, 0, 1); stageQ(0, 0, 2); stageQ(0, 0, 3);

  bf16x8 bfr[4];
  for (int t = 0; t < nt; ++t) {
    const int cur = t & 1;
    const int kt1 = (t + 1) * 64;
    const bool pf = (t + 1 < nt);
#pragma unroll
    for (int p = 0; p < 4; ++p) {
      if (pf) stageQ(cur ^ 1, kt1, p);
      if (p == 0) {
        if (pf) asm volatile("s_waitcnt vmcnt(2)" ::: "memory");
        else    asm volatile("s_waitcnt vmcnt(0)" ::: "memory");
        __builtin_amdgcn_s_barrier();
        asm volatile("" ::: "memory");
      }
      const int ks = p >> 1, miq = p & 1;
      bf16x8 af[4];
#pragma unroll
      for (int mi4 = 0; mi4 < 4; ++mi4) {
        const int arow = wm * 128 + (miq * 4 + mi4) * 16 + qr;
        const int ab = arow * 128 + ((grp * 16 + ks * 64) ^ ((arow & 7) << 4));
        af[mi4] = *(const bf16x8*)((const char*)&As[cur][0] + ab);
      }
      if (miq == 0) {
#pragma unroll
        for (int ni = 0; ni < 4; ++ni) {
          const int brow = wn * 64 + ni * 16 + qr;
          const int bb = brow * 128 + ((grp * 16 + ks * 64) ^ ((brow & 7) << 4));
          bfr[ni] = *(const bf16x8*)((const char*)&Bs[cur][0] + bb);
        }
      }
      __builtin_amdgcn_s_setprio(1);
#pragma unroll
      for (int mi4 = 0; mi4 < 4; ++mi4)
#pragma unroll
        for (int ni = 0; ni < 4; ++ni)
          acc[miq * 4 + mi4][ni] = __builtin_amdgcn_mfma_f32_16x16x32_bf16(
              bfr[ni], af[mi4], acc[miq * 4 + mi4][ni], 0, 0, 0);  // swapped
      __builtin_amdgcn_s_setprio(0);
      __builtin_amdgcn_s_barrier();
      asm volatile("" ::: "memory");
    }
  }

  // epilogue: lane holds C[m = m0+wm*128+mi*16+qr][n = n0+wn*64+ni*16+grp*4+r]
#pragma unroll
  for (int mi = 0; mi < 8; ++mi) {
    const int rowg = m0 + wm * 128 + mi * 16 + qr;
#pragma unroll
    for (int ni = 0; ni < 4; ++ni) {
      const int colg = n0 + wn * 64 + ni * 16 + grp * 4;
      float4 bv = *(const float4*)(bias + colg);
      float4 o;
      o.x = acc[mi][ni][0] + bv.x;
      o.y = acc[mi][ni][1] + bv.y;
      o.z = acc[mi][ni][2] + bv.z;
      o.w = acc[mi][ni][3] + bv.w;
      *(float4*)(C + (size_t)rowg * N + colg) = o;
    }
  }
}

// ---------------------------------------------------------------------------
// GEMM (layer GEMMs): 128x128 tile, BK=64, 8 waves (512 thr), dbuf,
// counted-vmcnt (4 loads/thread/tile -> vmcnt(4) = full-iteration cover).
// MODE 1: C=bf16 relu(acc+bias)    MODE 2: Hacc += acc (atomic if NSPLIT>1)
// MODE 3: Hacc += acc+bias (atomic, bias on split 0)
// MODE 5: QKV split: cols->q,k,Vt^T
// ---------------------------------------------------------------------------
template<int MODE, int NSPLIT>
__global__ __launch_bounds__(512) void gemm8_k(
    const bf16* __restrict__ A, const bf16* __restrict__ Bt,
    const float* __restrict__ bias, void* __restrict__ Cout,
    float* __restrict__ Hacc, bf16* __restrict__ Vt,
    int M, int N, int K)
{
  __shared__ __align__(16) bf16 As[2][128 * 64];
  __shared__ __align__(16) bf16 Bs[2][128 * 64];

  const int nwg = gridDim.x;
  const int orig = blockIdx.x;
  const int q8 = nwg >> 3, r8 = nwg & 7;
  const int xcd = orig & 7, loc = orig >> 3;
  const int wg = (xcd < r8 ? xcd * (q8 + 1) : r8 * (q8 + 1) + (xcd - r8) * q8) + loc;
  const int nrowt = M >> 7;
  const int ntiles = nrowt * (N >> 7);
  const int split = (NSPLIT > 1) ? (wg / ntiles) : 0;
  const int tile  = (NSPLIT > 1) ? (wg % ntiles) : wg;
  const int rowt = tile & (nrowt - 1);
  const int colt = tile / nrowt;
  const int m0 = rowt * 128;
  const int n0 = colt * 128;
  const int Ks = K / NSPLIT;
  const int k_begin = split * Ks;
  const int nt = Ks >> 6;

  const int tid = threadIdx.x;
  const int lane = tid & 63;
  const int wbase = tid & ~63;
  const int wid = tid >> 6;
  const int wm = wid >> 2;
  const int wn = wid & 3;
  const int qr = lane & 15, grp = lane >> 4;

  f32x4 acc[4][2];
#pragma unroll
  for (int i = 0; i < 4; ++i)
#pragma unroll
    for (int j = 0; j < 2; ++j) acc[i][j] = (f32x4){0.f, 0.f, 0.f, 0.f};

  auto stage = [&](int bufi, int kt) {
#pragma unroll
    for (int it = 0; it < 2; ++it) {
      const int idx = it * 512 + tid;
      const int row = idx >> 3, c = idx & 7;
      const int bo = (c * 16) ^ ((row & 7) << 4);
      gl_lds16((const char*)(A + (size_t)(m0 + row) * K + kt) + bo,
               (char*)&As[bufi][0] + (size_t)(it * 512 + wbase) * 16);
    }
#pragma unroll
    for (int it = 0; it < 2; ++it) {
      const int idx = it * 512 + tid;
      const int row = idx >> 3, c = idx & 7;
      const int bo = (c * 16) ^ ((row & 7) << 4);
      gl_lds16((const char*)(Bt + (size_t)(n0 + row) * K + kt) + bo,
               (char*)&Bs[bufi][0] + (size_t)(it * 512 + wbase) * 16);
    }
  };

  stage(0, k_begin);
  for (int t = 0; t < nt; ++t) {
    const int cur = t & 1;
    if (t + 1 < nt) {
      stage(cur ^ 1, k_begin + (t + 1) * 64);
      asm volatile("s_waitcnt vmcnt(4)" ::: "memory");
    } else {
      asm volatile("s_waitcnt vmcnt(0)" ::: "memory");
    }
    __builtin_amdgcn_s_barrier();
    asm volatile("" ::: "memory");
#pragma unroll
    for (int ks = 0; ks < 2; ++ks) {
      bf16x8 af[4], bfr[2];
#pragma unroll
      for (int mi = 0; mi < 4; ++mi) {
        const int arow = wm * 64 + mi * 16 + qr;
        const int ab = arow * 128 + ((grp * 16 + ks * 64) ^ ((arow & 7) << 4));
        af[mi] = *(const bf16x8*)((const char*)&As[cur][0] + ab);
      }
#pragma unroll
      for (int ni = 0; ni < 2; ++ni) {
        const int brow = wn * 32 + ni * 16 + qr;
        const int bb = brow * 128 + ((grp * 16 + ks * 64) ^ ((brow & 7) << 4));
        bfr[ni] = *(const bf16x8*)((const char*)&Bs[cur][0] + bb);
      }
      __builtin_amdgcn_s_setprio(1);
#pragma unroll
      for (int mi = 0; mi < 4; ++mi)
#pragma unroll
        for (int ni = 0; ni < 2; ++ni)
          acc[mi][ni] = __builtin_amdgcn_mfma_f32_16x16x32_bf16(
              af[mi], bfr[ni], acc[mi][ni], 0, 0, 0);
      __builtin_amdgcn_s_setprio(0);
    }
    __builtin_amdgcn_s_barrier();
    asm volatile("" ::: "memory");
  }

  const int sel = (MODE == 5) ? (n0 >> 10) : 0;
#pragma unroll
  for (int ni = 0; ni < 2; ++ni) {
    const int coln = wn * 32 + ni * 16 + qr;
    const int colg = n0 + coln;
    float bv = 0.f;
    if (MODE == 1) bv = bias[colg];
    if (MODE == 3 && split == 0) bv = bias[colg];
#pragma unroll
    for (int mi = 0; mi < 4; ++mi) {
      const int rowg0 = m0 + wm * 64 + mi * 16 + grp * 4;
      if (MODE == 5 && sel == 2) {
        const int b = rowg0 >> 10, s = rowg0 & 1023;
        bf16x4 pv;
#pragma unroll
        for (int r = 0; r < 4; ++r) pv[r] = (bf16)acc[mi][ni][r];
        *(bf16x4*)(Vt + (size_t)b * 1024 * 1024 + (size_t)(colg & 1023) * 1024 + s) = pv;
      } else {
#pragma unroll
        for (int r = 0; r < 4; ++r) {
          const int rowg = rowg0 + r;
          float v = acc[mi][ni][r];
          if (MODE == 1) {
            v += bv; v = v > 0.f ? v : 0.f;
            ((bf16*)Cout)[(size_t)rowg * N + colg] = (bf16)v;
          } else if (MODE == 2) {
            if (NSPLIT > 1) atomicAdd(&Hacc[(size_t)rowg * N + colg], v);
            else            Hacc[(size_t)rowg * N + colg] += v;
          } else if (MODE == 3) {
            if (NSPLIT > 1) atomicAdd(&Hacc[(size_t)rowg * N + colg], v + bv);
            else            Hacc[(size_t)rowg * N + colg] += v + bv;
          } else if (MODE == 5) {
            bf16* cb = (bf16*)Cout + (size_t)sel * 2048 * 1024;
            cb[(size_t)rowg * 1024 + (colg & 1023)] = (bf16)v;
          }
        }
      }
    }
  }
}

// ---------------------------------------------------------------------------
// Flash attention (unchanged).
// ---------------------------------------------------------------------------
__global__ __launch_bounds__(64) void attn_k(const bf16* __restrict__ qm,
    const bf16* __restrict__ km, const bf16* __restrict__ vt,
    bf16* __restrict__ om)
{
  const int lane = threadIdx.x;
  const int qr = lane & 15, g = lane >> 4;
  const int qt = blockIdx.x & 63;
  const int hh = (blockIdx.x >> 6) & 15;
  const int bb = blockIdx.x >> 10;
  const size_t rowb = (size_t)bb * 1024;
  const int hb = hh * 64;

  const bf16* qp = qm + (rowb + qt * 16 + qr) * 1024 + hb + g * 8;
  const bf16x8 qf0 = *(const bf16x8*)qp;
  const bf16x8 qf1 = *(const bf16x8*)(qp + 32);

  const float SC = 0.125f * 1.4426950408889634f;

  float m_run = -1e30f, l_run = 0.f;
  f32x4 oacc[4];
#pragma unroll
  for (int dt = 0; dt < 4; ++dt) oacc[dt] = (f32x4){0.f, 0.f, 0.f, 0.f};

  const int qglob = qt * 16 + qr;
  const bf16* vtb = vt + (size_t)bb * 1024 * 1024;
  const bf16* kbase = km + rowb * 1024 + hb;

  auto tile_step = [&](int kvt, bool masked) {
    const bf16* kp = kbase + (size_t)kvt * 16 * 1024 + qr * 1024 + g * 8;
    bf16x8 kf0 = *(const bf16x8*)kp;
    bf16x8 kf1 = *(const bf16x8*)(kp + 32);
    bf16x4 vf[4];
#pragma unroll
    for (int dt = 0; dt < 4; ++dt)
      vf[dt] = *(const bf16x4*)(vtb + (size_t)(hb + dt * 16 + qr) * 1024 + kvt * 16 + g * 4);
    f32x4 st = (f32x4){0.f, 0.f, 0.f, 0.f};
    st = __builtin_amdgcn_mfma_f32_16x16x32_bf16(kf0, qf0, st, 0, 0, 0);
    st = __builtin_amdgcn_mfma_f32_16x16x32_bf16(kf1, qf1, st, 0, 0, 0);
    float sc[4];
#pragma unroll
    for (int r = 0; r < 4; ++r) {
      sc[r] = st[r] * SC;
      if (masked && (kvt * 16 + g * 4 + r > qglob)) sc[r] = -1e30f;
    }
    float mloc = fmaxf(fmaxf(sc[0], sc[1]), fmaxf(sc[2], sc[3]));
    mloc = fmaxf(mloc, __shfl_xor(mloc, 16));
    mloc = fmaxf(mloc, __shfl_xor(mloc, 32));
    float m_new = fmaxf(m_run, mloc);
    float alpha = exp2f(m_run - m_new);
    float p[4], ps = 0.f;
#pragma unroll
    for (int r = 0; r < 4; ++r) { p[r] = exp2f(sc[r] - m_new); ps += p[r]; }
    ps += __shfl_xor(ps, 16);
    ps += __shfl_xor(ps, 32);
    l_run = l_run * alpha + ps;
    m_run = m_new;
    short4v pfa;
#pragma unroll
    for (int r = 0; r < 4; ++r) pfa[r] = f2bs(p[r]);
#pragma unroll
    for (int dt = 0; dt < 4; ++dt) {
      oacc[dt] *= alpha;
      oacc[dt] = __builtin_amdgcn_mfma_f32_16x16x16bf16_1k(
          __builtin_bit_cast(short4v, vf[dt]), pfa, oacc[dt], 0, 0, 0);
    }
  };

  const int nun = qt;
  int kvt = 0;
  for (; kvt + 3 < nun; kvt += 4) {
    bf16x8 kf[4][2];
#pragma unroll
    for (int tt = 0; tt < 4; ++tt) {
      const bf16* kp = kbase + (size_t)(kvt + tt) * 16 * 1024 + qr * 1024 + g * 8;
      kf[tt][0] = *(const bf16x8*)kp;
      kf[tt][1] = *(const bf16x8*)(kp + 32);
    }
    bf16x4 vf[4][4];
#pragma unroll
    for (int tt = 0; tt < 4; ++tt)
#pragma unroll
      for (int dt = 0; dt < 4; ++dt)
        vf[tt][dt] = *(const bf16x4*)(vtb + (size_t)(hb + dt * 16 + qr) * 1024
                                      + (kvt + tt) * 16 + g * 4);
    f32x4 st[4];
#pragma unroll
    for (int tt = 0; tt < 4; ++tt) {
      st[tt] = (f32x4){0.f, 0.f, 0.f, 0.f};
      st[tt] = __builtin_amdgcn_mfma_f32_16x16x32_bf16(kf[tt][0], qf0, st[tt], 0, 0, 0);
      st[tt] = __builtin_amdgcn_mfma_f32_16x16x32_bf16(kf[tt][1], qf1, st[tt], 0, 0, 0);
    }
    float p[4][4];
    float mloc = -1e30f;
#pragma unroll
    for (int tt = 0; tt < 4; ++tt)
#pragma unroll
      for (int r = 0; r < 4; ++r) {
        p[tt][r] = st[tt][r] * SC;
        mloc = fmaxf(mloc, p[tt][r]);
      }
    mloc = fmaxf(mloc, __shfl_xor(mloc, 16));
    mloc = fmaxf(mloc, __shfl_xor(mloc, 32));
    if (!__all(mloc <= m_run + 8.f)) {
      float m_new = fmaxf(m_run, mloc);
      float alpha = exp2f(m_run - m_new);
      l_run *= alpha;
#pragma unroll
      for (int dt = 0; dt < 4; ++dt) oacc[dt] *= alpha;
      m_run = m_new;
    }
    float ps = 0.f;
#pragma unroll
    for (int tt = 0; tt < 4; ++tt)
#pragma unroll
      for (int r = 0; r < 4; ++r) {
        p[tt][r] = exp2f(p[tt][r] - m_run);
        ps += p[tt][r];
      }
    ps += __shfl_xor(ps, 16);
    ps += __shfl_xor(ps, 32);
    l_run += ps;
    short4v pf[4];
#pragma unroll
    for (int tt = 0; tt < 4; ++tt)
#pragma unroll
      for (int r = 0; r < 4; ++r) pf[tt][r] = f2bs(p[tt][r]);
#pragma unroll
    for (int dt = 0; dt < 4; ++dt)
#pragma unroll
      for (int tt = 0; tt < 4; ++tt)
        oacc[dt] = __builtin_amdgcn_mfma_f32_16x16x16bf16_1k(
            __builtin_bit_cast(short4v, vf[tt][dt]), pf[tt], oacc[dt], 0, 0, 0);
  }
  for (; kvt < nun; ++kvt) tile_step(kvt, false);
  tile_step(qt, true);

  const float inv = 1.f / l_run;
  bf16* op = om + (rowb + qt * 16 + qr) * 1024 + hb;
#pragma unroll
  for (int dt = 0; dt < 4; ++dt)
#pragma unroll
    for (int r = 0; r < 4; ++r)
      op[dt * 16 + g * 4 + r] = (bf16)(oacc[dt][r] * inv);
}

// ---------------------------------------------------------------------------
extern "C" void kernel_launch(void* const* d_in, const int* in_sizes, int n_in,
                              void* d_out, int out_size, void* d_ws, size_t ws_size,
                              hipStream_t stream)
{
  (void)in_sizes; (void)n_in; (void)out_size; (void)ws_size;
  const int*   x     = (const int*)d_in[0];
  const float* emb   = (const float*)d_in[2];
  const float* Wq    = (const float*)d_in[3];
  const float* Wk    = (const float*)d_in[4];
  const float* Wv    = (const float*)d_in[5];
  const float* Wo    = (const float*)d_in[6];
  const float* ln1g  = (const float*)d_in[7];
  const float* ln1b  = (const float*)d_in[8];
  const float* ln2g  = (const float*)d_in[9];
  const float* ln2b  = (const float*)d_in[10];
  const float* W1    = (const float*)d_in[11];
  const float* b1    = (const float*)d_in[12];
  const float* W2    = (const float*)d_in[13];
  const float* b2    = (const float*)d_in[14];
  const float* lnfg  = (const float*)d_in[15];
  const float* lnfb  = (const float*)d_in[16];
  const float* projW = (const float*)d_in[17];
  const float* projb = (const float*)d_in[18];

  char* ws = (char*)d_ws;
  const size_t MB = 1u << 20;
  float* h    = (float*)(ws + 0);            // 8 MB
  bf16*  ain  = (bf16*)(ws + 8 * MB);        // 4 MB
  bf16*  qb   = (bf16*)(ws + 12 * MB);       // 4 MB
  bf16*  kb   = (bf16*)(ws + 16 * MB);       // 4 MB
  bf16*  vtb  = (bf16*)(ws + 20 * MB);       // 4 MB (V^T)
  bf16*  ob   = (bf16*)(ws + 24 * MB);       // 4 MB
  bf16*  mid  = (bf16*)(ws + 28 * MB);       // 16 MB
  bf16*  Bqkv = (bf16*)(ws + 44 * MB);       // 48 MB
  bf16*  Bo   = (bf16*)(ws + 92 * MB);       // 16 MB
  bf16*  B1t  = (bf16*)(ws + 108 * MB);      // 64 MB
  bf16*  B2t  = (bf16*)(ws + 172 * MB);      // 64 MB
  bf16*  Bprj = (bf16*)(ws + 236 * MB);      // 65.5 MB

  const long M1 = 1024 * 1024, M3 = 3 * M1, M4 = 4 * M1;

  wt4_k<<<dim3(32, 16, 32),  256, 0, stream>>>(Wq, Wk, Wv, Wo, Bqkv, Bo);
  wt_k<<<dim3(128, 16, 8),   256, 0, stream>>>(W1, B1t,     1024, 4096, M4, M4);
  wt_k<<<dim3(32, 64, 8),    256, 0, stream>>>(W2, B2t,     4096, 1024, M4, M4);
  wt_k<<<dim3(1000, 16, 1),  256, 0, stream>>>(projW, Bprj, 1024, 32000, 0, 0);

  embed_k<<<dim3(2048), 256, 0, stream>>>(x, emb, h);
  for (int i = 0; i < 8; ++i) {
    ln_k<<<dim3(2048), 256, 0, stream>>>(h, ln1g + i * 1024, ln1b + i * 1024, ain);
    gemm8_k<5,1><<<dim3(384), 512, 0, stream>>>(ain, Bqkv + i * M3, nullptr,
                                                qb, nullptr, vtb, 2048, 3072, 1024);
    attn_k<<<dim3(2048), 64, 0, stream>>>(qb, kb, vtb, ob);
    gemm8_k<2,4><<<dim3(512), 512, 0, stream>>>(ob, Bo + i * M1, nullptr,
                                                nullptr, h, nullptr, 2048, 1024, 1024);
    ln_k<<<dim3(2048), 256, 0, stream>>>(h, ln2g + i * 1024, ln2b + i * 1024, ain);
    gemm8_k<1,1><<<dim3(512), 512, 0, stream>>>(ain, B1t + i * M4, b1 + i * 4096,
                                                mid, nullptr, nullptr, 2048, 4096, 1024);
    gemm8_k<3,4><<<dim3(512), 512, 0, stream>>>(mid, B2t + i * M4, b2 + i * 1024,
                                                nullptr, h, nullptr, 2048, 1024, 4096);
  }
  ln_k<<<dim3(2048), 256, 0, stream>>>(h, lnfg, lnfb, ain);
  gemm256p_k<<<dim3(1000), 512, 0, stream>>>(ain, Bprj, projb,
                                             (float*)d_out, 2048, 32000, 1024);
}

// Round 10
// 2097.315 us; speedup vs baseline: 1.0339x; 1.0339x over previous
//
#include <hip/hip_runtime.h>

typedef __bf16 bf16;
typedef __bf16 bf16x4 __attribute__((ext_vector_type(4)));
typedef __bf16 bf16x8 __attribute__((ext_vector_type(8)));
typedef float f32x4 __attribute__((ext_vector_type(4)));
typedef short short4v __attribute__((ext_vector_type(4)));

__device__ __forceinline__ short f2bs(float x) {
  bf16 hv = (bf16)x;
  return __builtin_bit_cast(short, hv);
}

__device__ __forceinline__ void gl_lds16(const void* g, void* l) {
  __builtin_amdgcn_global_load_lds(
      (const __attribute__((address_space(1))) unsigned int*)g,
      (__attribute__((address_space(3))) unsigned int*)l, 16, 0, 0);
}

// ---------------------------------------------------------------------------
// Weight transpose+convert: fp32 [K][N] -> bf16 [N][K]; 64k x 32n tile.
// ---------------------------------------------------------------------------
__global__ __launch_bounds__(256) void wt_k(const float* __restrict__ in,
    bf16* __restrict__ out, int K, int N, long in_ls, long out_ls)
{
  __shared__ float t[64][33];
  const int z = blockIdx.z;
  const float* ip = in + (size_t)z * in_ls;
  bf16* op = out + (size_t)z * out_ls;
  const int n0 = blockIdx.x * 32, k0 = blockIdx.y * 64;
  const int tid = threadIdx.x;
  const int kr = tid >> 3, nc = (tid & 7) * 4;
#pragma unroll
  for (int hh = 0; hh < 2; ++hh) {
    float4 v = *(const float4*)(ip + (size_t)(k0 + kr + hh * 32) * N + n0 + nc);
    t[kr + hh * 32][nc]     = v.x;
    t[kr + hh * 32][nc + 1] = v.y;
    t[kr + hh * 32][nc + 2] = v.z;
    t[kr + hh * 32][nc + 3] = v.w;
  }
  __syncthreads();
  const int nr = tid >> 3, kc = (tid & 7) * 8;
  bf16x8 o;
#pragma unroll
  for (int j = 0; j < 8; ++j) o[j] = (bf16)t[kc + j][nr];
  *(bf16x8*)(op + (size_t)(n0 + nr) * K + k0 + kc) = o;
}

// Merged square-weight pre-pass: z -> {Wq,Wk,Wv,Wo} x layer (1024x1024 each)
__global__ __launch_bounds__(256) void wt4_k(const float* __restrict__ Wq,
    const float* __restrict__ Wk, const float* __restrict__ Wv,
    const float* __restrict__ Wo, bf16* __restrict__ Bqkv,
    bf16* __restrict__ Bo)
{
  __shared__ float t[64][33];
  const int z = blockIdx.z;
  const int which = z >> 3, layer = z & 7;
  const long M1 = 1024 * 1024, M3 = 3 * M1;
  const float* ip = (which == 0 ? Wq : which == 1 ? Wk : which == 2 ? Wv : Wo)
                    + (size_t)layer * M1;
  bf16* op = (which < 3) ? (Bqkv + (size_t)layer * M3 + (size_t)which * M1)
                         : (Bo + (size_t)layer * M1);
  const int n0 = blockIdx.x * 32, k0 = blockIdx.y * 64;
  const int tid = threadIdx.x;
  const int kr = tid >> 3, nc = (tid & 7) * 4;
#pragma unroll
  for (int hh = 0; hh < 2; ++hh) {
    float4 v = *(const float4*)(ip + (size_t)(k0 + kr + hh * 32) * 1024 + n0 + nc);
    t[kr + hh * 32][nc]     = v.x;
    t[kr + hh * 32][nc + 1] = v.y;
    t[kr + hh * 32][nc + 2] = v.z;
    t[kr + hh * 32][nc + 3] = v.w;
  }
  __syncthreads();
  const int nr = tid >> 3, kc = (tid & 7) * 8;
  bf16x8 o;
#pragma unroll
  for (int j = 0; j < 8; ++j) o[j] = (bf16)t[kc + j][nr];
  *(bf16x8*)(op + (size_t)(n0 + nr) * 1024 + k0 + kc) = o;
}

// ---------------------------------------------------------------------------
// Embedding: h[m][d] = emb[x[m]][d]*32 + PE(s,d)
// ---------------------------------------------------------------------------
__global__ __launch_bounds__(256) void embed_k(const int* __restrict__ x,
    const float* __restrict__ emb, float* __restrict__ h)
{
  const int m = blockIdx.x, t = threadIdx.x;
  const int s = m & 1023;
  const int tok = x[m];
  const int d0 = t * 4;
  float4 e = *(const float4*)(emb + (size_t)tok * 1024 + d0);
  const float* ep = &e.x;
  float r[4];
#pragma unroll
  for (int j = 0; j < 4; ++j) {
    int d = d0 + j;
    float freq = expf((float)(d & ~1) * (-9.2103403719761836f / 1024.f));
    float ang = (float)s * freq;
    float pe = (d & 1) ? cosf(ang) : sinf(ang);
    r[j] = ep[j] * 32.f + pe;
  }
  *(float4*)(h + (size_t)m * 1024 + d0) = make_float4(r[0], r[1], r[2], r[3]);
}

// ---------------------------------------------------------------------------
// LayerNorm (fp32 in, bf16 out), one block per row of 1024
// ---------------------------------------------------------------------------
__global__ __launch_bounds__(256) void ln_k(const float* __restrict__ h,
    const float* __restrict__ g, const float* __restrict__ b,
    bf16* __restrict__ out)
{
  const int row = blockIdx.x, t = threadIdx.x;
  const float* hr = h + (size_t)row * 1024;
  float4 x = *(const float4*)(hr + t * 4);
  float s  = x.x + x.y + x.z + x.w;
  float ss = x.x * x.x + x.y * x.y + x.z * x.z + x.w * x.w;
#pragma unroll
  for (int off = 32; off >= 1; off >>= 1) {
    s  += __shfl_down(s, off);
    ss += __shfl_down(ss, off);
  }
  __shared__ float sb[4], ssb[4];
  if ((t & 63) == 0) { sb[t >> 6] = s; ssb[t >> 6] = ss; }
  __syncthreads();
  s  = sb[0] + sb[1] + sb[2] + sb[3];
  ss = ssb[0] + ssb[1] + ssb[2] + ssb[3];
  const float mean = s * (1.f / 1024.f);
  const float var  = ss * (1.f / 1024.f) - mean * mean;
  const float rstd = rsqrtf(var + 1e-5f);
  const float* xp = &x.x;
#pragma unroll
  for (int j = 0; j < 4; ++j) {
    int d = t * 4 + j;
    out[(size_t)row * 1024 + d] = (bf16)((xp[j] - mean) * rstd * g[d] + b[d]);
  }
}

// ---------------------------------------------------------------------------
// GEMM 256x256 (proj, r5 best ~714 TF): counted-vmcnt, 16 waves,
// operand-swapped MFMA -> coalesced float4 C stores.
// ---------------------------------------------------------------------------
__global__ __launch_bounds__(1024) void gemm256_k(
    const bf16* __restrict__ A, const bf16* __restrict__ Bt,
    const float* __restrict__ bias, float* __restrict__ C,
    int M, int N, int K)
{
  __shared__ __align__(16) bf16 As[2][256 * 64];
  __shared__ __align__(16) bf16 Bs[2][256 * 64];

  const int nwg = gridDim.x;
  const int orig = blockIdx.x;
  const int q8 = nwg >> 3, r8 = nwg & 7;
  const int xcd = orig & 7, loc = orig >> 3;
  const int wg = (xcd < r8 ? xcd * (q8 + 1) : r8 * (q8 + 1) + (xcd - r8) * q8) + loc;
  const int nrowt = M >> 8;
  const int rowt = wg & (nrowt - 1);
  const int colt = wg / nrowt;
  const int m0 = rowt * 256;
  const int n0 = colt * 256;
  const int nt = K >> 6;

  const int tid = threadIdx.x;
  const int lane = tid & 63;
  const int wbase = tid & ~63;
  const int wid = tid >> 6;
  const int wm = wid >> 2, wn = wid & 3;
  const int qr = lane & 15, grp = lane >> 4;

  f32x4 acc[4][4];
#pragma unroll
  for (int i = 0; i < 4; ++i)
#pragma unroll
    for (int j = 0; j < 4; ++j) acc[i][j] = (f32x4){0.f, 0.f, 0.f, 0.f};

  auto stage = [&](int bufi, int kt) {
#pragma unroll
    for (int it = 0; it < 2; ++it) {
      const int idx = it * 1024 + tid;
      const int row = idx >> 3, c = idx & 7;
      const int bo = (c * 16) ^ ((row & 7) << 4);
      gl_lds16((const char*)(A + (size_t)(m0 + row) * K + kt) + bo,
               (char*)&As[bufi][0] + (size_t)(it * 1024 + wbase) * 16);
    }
#pragma unroll
    for (int it = 0; it < 2; ++it) {
      const int idx = it * 1024 + tid;
      const int row = idx >> 3, c = idx & 7;
      const int bo = (c * 16) ^ ((row & 7) << 4);
      gl_lds16((const char*)(Bt + (size_t)(n0 + row) * K + kt) + bo,
               (char*)&Bs[bufi][0] + (size_t)(it * 1024 + wbase) * 16);
    }
  };

  stage(0, 0);
  for (int t = 0; t < nt; ++t) {
    const int cur = t & 1;
    if (t + 1 < nt) {
      stage(cur ^ 1, (t + 1) * 64);
      asm volatile("s_waitcnt vmcnt(4)" ::: "memory");
    } else {
      asm volatile("s_waitcnt vmcnt(0)" ::: "memory");
    }
    __builtin_amdgcn_s_barrier();
    asm volatile("" ::: "memory");
#pragma unroll
    for (int ks = 0; ks < 2; ++ks) {
      bf16x8 af[4], bfr[4];
#pragma unroll
      for (int mi = 0; mi < 4; ++mi) {
        const int arow = wm * 64 + mi * 16 + qr;
        const int ab = arow * 128 + ((grp * 16 + ks * 64) ^ ((arow & 7) << 4));
        af[mi] = *(const bf16x8*)((const char*)&As[cur][0] + ab);
      }
#pragma unroll
      for (int ni = 0; ni < 4; ++ni) {
        const int brow = wn * 64 + ni * 16 + qr;
        const int bb = brow * 128 + ((grp * 16 + ks * 64) ^ ((brow & 7) << 4));
        bfr[ni] = *(const bf16x8*)((const char*)&Bs[cur][0] + bb);
      }
      __builtin_amdgcn_s_setprio(1);
#pragma unroll
      for (int mi = 0; mi < 4; ++mi)
#pragma unroll
        for (int ni = 0; ni < 4; ++ni)
          acc[mi][ni] = __builtin_amdgcn_mfma_f32_16x16x32_bf16(
              bfr[ni], af[mi], acc[mi][ni], 0, 0, 0);  // swapped: rows<->n
      __builtin_amdgcn_s_setprio(0);
    }
    __builtin_amdgcn_s_barrier();
    asm volatile("" ::: "memory");
  }

#pragma unroll
  for (int mi = 0; mi < 4; ++mi) {
    const int rowg = m0 + wm * 64 + mi * 16 + qr;
#pragma unroll
    for (int ni = 0; ni < 4; ++ni) {
      const int colg = n0 + wn * 64 + ni * 16 + grp * 4;
      float4 bv = *(const float4*)(bias + colg);
      float4 o;
      o.x = acc[mi][ni][0] + bv.x;
      o.y = acc[mi][ni][1] + bv.y;
      o.z = acc[mi][ni][2] + bv.z;
      o.w = acc[mi][ni][3] + bv.w;
      *(float4*)(C + (size_t)rowg * N + colg) = o;
    }
  }
}

// ---------------------------------------------------------------------------
// GEMM (layer GEMMs): 128x128 tile, BK=64, 8 waves (512 thr), dbuf,
// counted-vmcnt (4 loads/thread/tile -> vmcnt(4) = full-iteration cover).
// MODE 1: C=bf16 relu(acc+bias)    MODE 2: Hacc += acc (atomic if NSPLIT>1)
// MODE 3: Hacc += acc+bias (atomic, bias on split 0)
// MODE 5: QKV split: cols->q,k,Vt^T
// ---------------------------------------------------------------------------
template<int MODE, int NSPLIT>
__global__ __launch_bounds__(512) void gemm8_k(
    const bf16* __restrict__ A, const bf16* __restrict__ Bt,
    const float* __restrict__ bias, void* __restrict__ Cout,
    float* __restrict__ Hacc, bf16* __restrict__ Vt,
    int M, int N, int K)
{
  __shared__ __align__(16) bf16 As[2][128 * 64];
  __shared__ __align__(16) bf16 Bs[2][128 * 64];

  const int nwg = gridDim.x;
  const int orig = blockIdx.x;
  const int q8 = nwg >> 3, r8 = nwg & 7;
  const int xcd = orig & 7, loc = orig >> 3;
  const int wg = (xcd < r8 ? xcd * (q8 + 1) : r8 * (q8 + 1) + (xcd - r8) * q8) + loc;
  const int nrowt = M >> 7;
  const int ntiles = nrowt * (N >> 7);
  const int split = (NSPLIT > 1) ? (wg / ntiles) : 0;
  const int tile  = (NSPLIT > 1) ? (wg % ntiles) : wg;
  const int rowt = tile & (nrowt - 1);
  const int colt = tile / nrowt;
  const int m0 = rowt * 128;
  const int n0 = colt * 128;
  const int Ks = K / NSPLIT;
  const int k_begin = split * Ks;
  const int nt = Ks >> 6;

  const int tid = threadIdx.x;
  const int lane = tid & 63;
  const int wbase = tid & ~63;
  const int wid = tid >> 6;
  const int wm = wid >> 2;
  const int wn = wid & 3;
  const int qr = lane & 15, grp = lane >> 4;

  f32x4 acc[4][2];
#pragma unroll
  for (int i = 0; i < 4; ++i)
#pragma unroll
    for (int j = 0; j < 2; ++j) acc[i][j] = (f32x4){0.f, 0.f, 0.f, 0.f};

  auto stage = [&](int bufi, int kt) {
#pragma unroll
    for (int it = 0; it < 2; ++it) {
      const int idx = it * 512 + tid;
      const int row = idx >> 3, c = idx & 7;
      const int bo = (c * 16) ^ ((row & 7) << 4);
      gl_lds16((const char*)(A + (size_t)(m0 + row) * K + kt) + bo,
               (char*)&As[bufi][0] + (size_t)(it * 512 + wbase) * 16);
    }
#pragma unroll
    for (int it = 0; it < 2; ++it) {
      const int idx = it * 512 + tid;
      const int row = idx >> 3, c = idx & 7;
      const int bo = (c * 16) ^ ((row & 7) << 4);
      gl_lds16((const char*)(Bt + (size_t)(n0 + row) * K + kt) + bo,
               (char*)&Bs[bufi][0] + (size_t)(it * 512 + wbase) * 16);
    }
  };

  stage(0, k_begin);
  for (int t = 0; t < nt; ++t) {
    const int cur = t & 1;
    if (t + 1 < nt) {
      stage(cur ^ 1, k_begin + (t + 1) * 64);
      asm volatile("s_waitcnt vmcnt(4)" ::: "memory");
    } else {
      asm volatile("s_waitcnt vmcnt(0)" ::: "memory");
    }
    __builtin_amdgcn_s_barrier();
    asm volatile("" ::: "memory");
#pragma unroll
    for (int ks = 0; ks < 2; ++ks) {
      bf16x8 af[4], bfr[2];
#pragma unroll
      for (int mi = 0; mi < 4; ++mi) {
        const int arow = wm * 64 + mi * 16 + qr;
        const int ab = arow * 128 + ((grp * 16 + ks * 64) ^ ((arow & 7) << 4));
        af[mi] = *(const bf16x8*)((const char*)&As[cur][0] + ab);
      }
#pragma unroll
      for (int ni = 0; ni < 2; ++ni) {
        const int brow = wn * 32 + ni * 16 + qr;
        const int bb = brow * 128 + ((grp * 16 + ks * 64) ^ ((brow & 7) << 4));
        bfr[ni] = *(const bf16x8*)((const char*)&Bs[cur][0] + bb);
      }
      __builtin_amdgcn_s_setprio(1);
#pragma unroll
      for (int mi = 0; mi < 4; ++mi)
#pragma unroll
        for (int ni = 0; ni < 2; ++ni)
          acc[mi][ni] = __builtin_amdgcn_mfma_f32_16x16x32_bf16(
              af[mi], bfr[ni], acc[mi][ni], 0, 0, 0);
      __builtin_amdgcn_s_setprio(0);
    }
    __builtin_amdgcn_s_barrier();
    asm volatile("" ::: "memory");
  }

  const int sel = (MODE == 5) ? (n0 >> 10) : 0;
#pragma unroll
  for (int ni = 0; ni < 2; ++ni) {
    const int coln = wn * 32 + ni * 16 + qr;
    const int colg = n0 + coln;
    float bv = 0.f;
    if (MODE == 1) bv = bias[colg];
    if (MODE == 3 && split == 0) bv = bias[colg];
#pragma unroll
    for (int mi = 0; mi < 4; ++mi) {
      const int rowg0 = m0 + wm * 64 + mi * 16 + grp * 4;
      if (MODE == 5 && sel == 2) {
        const int b = rowg0 >> 10, s = rowg0 & 1023;
        bf16x4 pv;
#pragma unroll
        for (int r = 0; r < 4; ++r) pv[r] = (bf16)acc[mi][ni][r];
        *(bf16x4*)(Vt + (size_t)b * 1024 * 1024 + (size_t)(colg & 1023) * 1024 + s) = pv;
      } else {
#pragma unroll
        for (int r = 0; r < 4; ++r) {
          const int rowg = rowg0 + r;
          float v = acc[mi][ni][r];
          if (MODE == 1) {
            v += bv; v = v > 0.f ? v : 0.f;
            ((bf16*)Cout)[(size_t)rowg * N + colg] = (bf16)v;
          } else if (MODE == 2) {
            if (NSPLIT > 1) atomicAdd(&Hacc[(size_t)rowg * N + colg], v);
            else            Hacc[(size_t)rowg * N + colg] += v;
          } else if (MODE == 3) {
            if (NSPLIT > 1) atomicAdd(&Hacc[(size_t)rowg * N + colg], v + bv);
            else            Hacc[(size_t)rowg * N + colg] += v + bv;
          } else if (MODE == 5) {
            bf16* cb = (bf16*)Cout + (size_t)sel * 2048 * 1024;
            cb[(size_t)rowg * 1024 + (colg & 1023)] = (bf16)v;
          }
        }
      }
    }
  }
}

// ---------------------------------------------------------------------------
// Flash attention (round-7/8 version).
// ---------------------------------------------------------------------------
__global__ __launch_bounds__(64) void attn_k(const bf16* __restrict__ qm,
    const bf16* __restrict__ km, const bf16* __restrict__ vt,
    bf16* __restrict__ om)
{
  const int lane = threadIdx.x;
  const int qr = lane & 15, g = lane >> 4;
  const int qt = blockIdx.x & 63;
  const int hh = (blockIdx.x >> 6) & 15;
  const int bb = blockIdx.x >> 10;
  const size_t rowb = (size_t)bb * 1024;
  const int hb = hh * 64;

  const bf16* qp = qm + (rowb + qt * 16 + qr) * 1024 + hb + g * 8;
  const bf16x8 qf0 = *(const bf16x8*)qp;
  const bf16x8 qf1 = *(const bf16x8*)(qp + 32);

  const float SC = 0.125f * 1.4426950408889634f;

  float m_run = -1e30f, l_run = 0.f;
  f32x4 oacc[4];
#pragma unroll
  for (int dt = 0; dt < 4; ++dt) oacc[dt] = (f32x4){0.f, 0.f, 0.f, 0.f};

  const int qglob = qt * 16 + qr;
  const bf16* vtb = vt + (size_t)bb * 1024 * 1024;
  const bf16* kbase = km + rowb * 1024 + hb;

  auto tile_step = [&](int kvt, bool masked) {
    const bf16* kp = kbase + (size_t)kvt * 16 * 1024 + qr * 1024 + g * 8;
    bf16x8 kf0 = *(const bf16x8*)kp;
    bf16x8 kf1 = *(const bf16x8*)(kp + 32);
    bf16x4 vf[4];
#pragma unroll
    for (int dt = 0; dt < 4; ++dt)
      vf[dt] = *(const bf16x4*)(vtb + (size_t)(hb + dt * 16 + qr) * 1024 + kvt * 16 + g * 4);
    f32x4 st = (f32x4){0.f, 0.f, 0.f, 0.f};
    st = __builtin_amdgcn_mfma_f32_16x16x32_bf16(kf0, qf0, st, 0, 0, 0);
    st = __builtin_amdgcn_mfma_f32_16x16x32_bf16(kf1, qf1, st, 0, 0, 0);
    float sc[4];
#pragma unroll
    for (int r = 0; r < 4; ++r) {
      sc[r] = st[r] * SC;
      if (masked && (kvt * 16 + g * 4 + r > qglob)) sc[r] = -1e30f;
    }
    float mloc = fmaxf(fmaxf(sc[0], sc[1]), fmaxf(sc[2], sc[3]));
    mloc = fmaxf(mloc, __shfl_xor(mloc, 16));
    mloc = fmaxf(mloc, __shfl_xor(mloc, 32));
    float m_new = fmaxf(m_run, mloc);
    float alpha = exp2f(m_run - m_new);
    float p[4], ps = 0.f;
#pragma unroll
    for (int r = 0; r < 4; ++r) { p[r] = exp2f(sc[r] - m_new); ps += p[r]; }
    ps += __shfl_xor(ps, 16);
    ps += __shfl_xor(ps, 32);
    l_run = l_run * alpha + ps;
    m_run = m_new;
    short4v pfa;
#pragma unroll
    for (int r = 0; r < 4; ++r) pfa[r] = f2bs(p[r]);
#pragma unroll
    for (int dt = 0; dt < 4; ++dt) {
      oacc[dt] *= alpha;
      oacc[dt] = __builtin_amdgcn_mfma_f32_16x16x16bf16_1k(
          __builtin_bit_cast(short4v, vf[dt]), pfa, oacc[dt], 0, 0, 0);
    }
  };

  const int nun = qt;
  int kvt = 0;
  for (; kvt + 3 < nun; kvt += 4) {
    bf16x8 kf[4][2];
#pragma unroll
    for (int tt = 0; tt < 4; ++tt) {
      const bf16* kp = kbase + (size_t)(kvt + tt) * 16 * 1024 + qr * 1024 + g * 8;
      kf[tt][0] = *(const bf16x8*)kp;
      kf[tt][1] = *(const bf16x8*)(kp + 32);
    }
    bf16x4 vf[4][4];
#pragma unroll
    for (int tt = 0; tt < 4; ++tt)
#pragma unroll
      for (int dt = 0; dt < 4; ++dt)
        vf[tt][dt] = *(const bf16x4*)(vtb + (size_t)(hb + dt * 16 + qr) * 1024
                                      + (kvt + tt) * 16 + g * 4);
    f32x4 st[4];
#pragma unroll
    for (int tt = 0; tt < 4; ++tt) {
      st[tt] = (f32x4){0.f, 0.f, 0.f, 0.f};
      st[tt] = __builtin_amdgcn_mfma_f32_16x16x32_bf16(kf[tt][0], qf0, st[tt], 0, 0, 0);
      st[tt] = __builtin_amdgcn_mfma_f32_16x16x32_bf16(kf[tt][1], qf1, st[tt], 0, 0, 0);
    }
    float p[4][4];
    float mloc = -1e30f;
#pragma unroll
    for (int tt = 0; tt < 4; ++tt)
#pragma unroll
      for (int r = 0; r < 4; ++r) {
        p[tt][r] = st[tt][r] * SC;
        mloc = fmaxf(mloc, p[tt][r]);
      }
    mloc = fmaxf(mloc, __shfl_xor(mloc, 16));
    mloc = fmaxf(mloc, __shfl_xor(mloc, 32));
    if (!__all(mloc <= m_run + 8.f)) {
      float m_new = fmaxf(m_run, mloc);
      float alpha = exp2f(m_run - m_new);
      l_run *= alpha;
#pragma unroll
      for (int dt = 0; dt < 4; ++dt) oacc[dt] *= alpha;
      m_run = m_new;
    }
    float ps = 0.f;
#pragma unroll
    for (int tt = 0; tt < 4; ++tt)
#pragma unroll
      for (int r = 0; r < 4; ++r) {
        p[tt][r] = exp2f(p[tt][r] - m_run);
        ps += p[tt][r];
      }
    ps += __shfl_xor(ps, 16);
    ps += __shfl_xor(ps, 32);
    l_run += ps;
    short4v pf[4];
#pragma unroll
    for (int tt = 0; tt < 4; ++tt)
#pragma unroll
      for (int r = 0; r < 4; ++r) pf[tt][r] = f2bs(p[tt][r]);
#pragma unroll
    for (int dt = 0; dt < 4; ++dt)
#pragma unroll
      for (int tt = 0; tt < 4; ++tt)
        oacc[dt] = __builtin_amdgcn_mfma_f32_16x16x16bf16_1k(
            __builtin_bit_cast(short4v, vf[tt][dt]), pf[tt], oacc[dt], 0, 0, 0);
  }
  for (; kvt < nun; ++kvt) tile_step(kvt, false);
  tile_step(qt, true);

  const float inv = 1.f / l_run;
  bf16* op = om + (rowb + qt * 16 + qr) * 1024 + hb;
#pragma unroll
  for (int dt = 0; dt < 4; ++dt)
#pragma unroll
    for (int r = 0; r < 4; ++r)
      op[dt * 16 + g * 4 + r] = (bf16)(oacc[dt][r] * inv);
}

// ---------------------------------------------------------------------------
extern "C" void kernel_launch(void* const* d_in, const int* in_sizes, int n_in,
                              void* d_out, int out_size, void* d_ws, size_t ws_size,
                              hipStream_t stream)
{
  (void)in_sizes; (void)n_in; (void)out_size; (void)ws_size;
  const int*   x     = (const int*)d_in[0];
  const float* emb   = (const float*)d_in[2];
  const float* Wq    = (const float*)d_in[3];
  const float* Wk    = (const float*)d_in[4];
  const float* Wv    = (const float*)d_in[5];
  const float* Wo    = (const float*)d_in[6];
  const float* ln1g  = (const float*)d_in[7];
  const float* ln1b  = (const float*)d_in[8];
  const float* ln2g  = (const float*)d_in[9];
  const float* ln2b  = (const float*)d_in[10];
  const float* W1    = (const float*)d_in[11];
  const float* b1    = (const float*)d_in[12];
  const float* W2    = (const float*)d_in[13];
  const float* b2    = (const float*)d_in[14];
  const float* lnfg  = (const float*)d_in[15];
  const float* lnfb  = (const float*)d_in[16];
  const float* projW = (const float*)d_in[17];
  const float* projb = (const float*)d_in[18];

  char* ws = (char*)d_ws;
  const size_t MB = 1u << 20;
  float* h    = (float*)(ws + 0);            // 8 MB
  bf16*  ain  = (bf16*)(ws + 8 * MB);        // 4 MB
  bf16*  qb   = (bf16*)(ws + 12 * MB);       // 4 MB
  bf16*  kb   = (bf16*)(ws + 16 * MB);       // 4 MB
  bf16*  vtb  = (bf16*)(ws + 20 * MB);       // 4 MB (V^T)
  bf16*  ob   = (bf16*)(ws + 24 * MB);       // 4 MB
  bf16*  mid  = (bf16*)(ws + 28 * MB);       // 16 MB
  bf16*  Bqkv = (bf16*)(ws + 44 * MB);       // 48 MB
  bf16*  Bo   = (bf16*)(ws + 92 * MB);       // 16 MB
  bf16*  B1t  = (bf16*)(ws + 108 * MB);      // 64 MB
  bf16*  B2t  = (bf16*)(ws + 172 * MB);      // 64 MB
  bf16*  Bprj = (bf16*)(ws + 236 * MB);      // 65.5 MB

  const long M1 = 1024 * 1024, M3 = 3 * M1, M4 = 4 * M1;

  wt4_k<<<dim3(32, 16, 32),  256, 0, stream>>>(Wq, Wk, Wv, Wo, Bqkv, Bo);
  wt_k<<<dim3(128, 16, 8),   256, 0, stream>>>(W1, B1t,     1024, 4096, M4, M4);
  wt_k<<<dim3(32, 64, 8),    256, 0, stream>>>(W2, B2t,     4096, 1024, M4, M4);
  wt_k<<<dim3(1000, 16, 1),  256, 0, stream>>>(projW, Bprj, 1024, 32000, 0, 0);

  embed_k<<<dim3(2048), 256, 0, stream>>>(x, emb, h);
  for (int i = 0; i < 8; ++i) {
    ln_k<<<dim3(2048), 256, 0, stream>>>(h, ln1g + i * 1024, ln1b + i * 1024, ain);
    gemm8_k<5,1><<<dim3(384), 512, 0, stream>>>(ain, Bqkv + i * M3, nullptr,
                                                qb, nullptr, vtb, 2048, 3072, 1024);
    attn_k<<<dim3(2048), 64, 0, stream>>>(qb, kb, vtb, ob);
    gemm8_k<2,2><<<dim3(256), 512, 0, stream>>>(ob, Bo + i * M1, nullptr,
                                                nullptr, h, nullptr, 2048, 1024, 1024);
    ln_k<<<dim3(2048), 256, 0, stream>>>(h, ln2g + i * 1024, ln2b + i * 1024, ain);
    gemm8_k<1,1><<<dim3(512), 512, 0, stream>>>(ain, B1t + i * M4, b1 + i * 4096,
                                                mid, nullptr, nullptr, 2048, 4096, 1024);
    gemm8_k<3,2><<<dim3(256), 512, 0, stream>>>(mid, B2t + i * M4, b2 + i * 1024,
                                                nullptr, h, nullptr, 2048, 1024, 4096);
  }
  ln_k<<<dim3(2048), 256, 0, stream>>>(h, lnfg, lnfb, ain);
  gemm256_k<<<dim3(1000), 1024, 0, stream>>>(ain, Bprj, projb,
                                             (float*)d_out, 2048, 32000, 1024);
}

// Round 11
// 2084.806 us; speedup vs baseline: 1.0401x; 1.0060x over previous
//
#include <hip/hip_runtime.h>

typedef __bf16 bf16;
typedef __bf16 bf16x4 __attribute__((ext_vector_type(4)));
typedef __bf16 bf16x8 __attribute__((ext_vector_type(8)));
typedef float f32x4 __attribute__((ext_vector_type(4)));
typedef short short4v __attribute__((ext_vector_type(4)));

__device__ __forceinline__ short f2bs(float x) {
  bf16 hv = (bf16)x;
  return __builtin_bit_cast(short, hv);
}

__device__ __forceinline__ void gl_lds16(const void* g, void* l) {
  __builtin_amdgcn_global_load_lds(
      (const __attribute__((address_space(1))) unsigned int*)g,
      (__attribute__((address_space(3))) unsigned int*)l, 16, 0, 0);
}

// ---------------------------------------------------------------------------
// Merged weight pre-pass: fp32 [K][N] -> bf16 [N][K] for ALL weights in one
// launch (flat grid, region-decoded). 64k x 32n tile per block.
//   [0,16384)      square weights {Wq,Wk,Wv,Wo} x 8 layers (1024x1024)
//   [16384,32768)  W1  [8] 1024x4096
//   [32768,49152)  W2  [8] 4096x1024
//   [49152,65152)  proj 1024x32000
// ---------------------------------------------------------------------------
__global__ __launch_bounds__(256) void wtall_k(
    const float* __restrict__ Wq, const float* __restrict__ Wk,
    const float* __restrict__ Wv, const float* __restrict__ Wo,
    const float* __restrict__ W1, const float* __restrict__ W2,
    const float* __restrict__ Pw,
    bf16* __restrict__ Bqkv, bf16* __restrict__ Bo,
    bf16* __restrict__ B1t, bf16* __restrict__ B2t, bf16* __restrict__ Bprj)
{
  __shared__ float t[64][33];
  const long M1 = 1024 * 1024, M3 = 3 * M1, M4 = 4 * M1;
  int b = blockIdx.x;
  const float* ip; bf16* op; int K, N, n0, k0;
  if (b < 16384) {
    const int x = b & 31, y = (b >> 5) & 15, z = b >> 9;
    const int which = z >> 3, layer = z & 7;
    ip = (which == 0 ? Wq : which == 1 ? Wk : which == 2 ? Wv : Wo)
         + (size_t)layer * M1;
    op = (which < 3) ? (Bqkv + (size_t)layer * M3 + (size_t)which * M1)
                     : (Bo + (size_t)layer * M1);
    K = 1024; N = 1024; n0 = x * 32; k0 = y * 64;
  } else if (b < 32768) {
    b -= 16384;
    const int x = b & 127, y = (b >> 7) & 15, z = b >> 11;
    ip = W1 + (size_t)z * M4; op = B1t + (size_t)z * M4;
    K = 1024; N = 4096; n0 = x * 32; k0 = y * 64;
  } else if (b < 49152) {
    b -= 32768;
    const int x = b & 31, y = (b >> 5) & 63, z = b >> 11;
    ip = W2 + (size_t)z * M4; op = B2t + (size_t)z * M4;
    K = 4096; N = 1024; n0 = x * 32; k0 = y * 64;
  } else {
    b -= 49152;
    const int x = b % 1000, y = b / 1000;
    ip = Pw; op = Bprj;
    K = 1024; N = 32000; n0 = x * 32; k0 = y * 64;
  }
  const int tid = threadIdx.x;
  const int kr = tid >> 3, nc = (tid & 7) * 4;
#pragma unroll
  for (int hh = 0; hh < 2; ++hh) {
    float4 v = *(const float4*)(ip + (size_t)(k0 + kr + hh * 32) * N + n0 + nc);
    t[kr + hh * 32][nc]     = v.x;
    t[kr + hh * 32][nc + 1] = v.y;
    t[kr + hh * 32][nc + 2] = v.z;
    t[kr + hh * 32][nc + 3] = v.w;
  }
  __syncthreads();
  const int nr = tid >> 3, kc = (tid & 7) * 8;
  bf16x8 o;
#pragma unroll
  for (int j = 0; j < 8; ++j) o[j] = (bf16)t[kc + j][nr];
  *(bf16x8*)(op + (size_t)(n0 + nr) * K + k0 + kc) = o;
}

// ---------------------------------------------------------------------------
// Embedding: h[m][d] = emb[x[m]][d]*32 + PE(s,d)
// ---------------------------------------------------------------------------
__global__ __launch_bounds__(256) void embed_k(const int* __restrict__ x,
    const float* __restrict__ emb, float* __restrict__ h)
{
  const int m = blockIdx.x, t = threadIdx.x;
  const int s = m & 1023;
  const int tok = x[m];
  const int d0 = t * 4;
  float4 e = *(const float4*)(emb + (size_t)tok * 1024 + d0);
  const float* ep = &e.x;
  float r[4];
#pragma unroll
  for (int j = 0; j < 4; ++j) {
    int d = d0 + j;
    float freq = expf((float)(d & ~1) * (-9.2103403719761836f / 1024.f));
    float ang = (float)s * freq;
    float pe = (d & 1) ? cosf(ang) : sinf(ang);
    r[j] = ep[j] * 32.f + pe;
  }
  *(float4*)(h + (size_t)m * 1024 + d0) = make_float4(r[0], r[1], r[2], r[3]);
}

// ---------------------------------------------------------------------------
// LayerNorm (fp32 in, bf16 out), one block per row of 1024
// ---------------------------------------------------------------------------
__global__ __launch_bounds__(256) void ln_k(const float* __restrict__ h,
    const float* __restrict__ g, const float* __restrict__ b,
    bf16* __restrict__ out)
{
  const int row = blockIdx.x, t = threadIdx.x;
  const float* hr = h + (size_t)row * 1024;
  float4 x = *(const float4*)(hr + t * 4);
  float s  = x.x + x.y + x.z + x.w;
  float ss = x.x * x.x + x.y * x.y + x.z * x.z + x.w * x.w;
#pragma unroll
  for (int off = 32; off >= 1; off >>= 1) {
    s  += __shfl_down(s, off);
    ss += __shfl_down(ss, off);
  }
  __shared__ float sb[4], ssb[4];
  if ((t & 63) == 0) { sb[t >> 6] = s; ssb[t >> 6] = ss; }
  __syncthreads();
  s  = sb[0] + sb[1] + sb[2] + sb[3];
  ss = ssb[0] + ssb[1] + ssb[2] + ssb[3];
  const float mean = s * (1.f / 1024.f);
  const float var  = ss * (1.f / 1024.f) - mean * mean;
  const float rstd = rsqrtf(var + 1e-5f);
  const float* xp = &x.x;
#pragma unroll
  for (int j = 0; j < 4; ++j) {
    int d = t * 4 + j;
    out[(size_t)row * 1024 + d] = (bf16)((xp[j] - mean) * rstd * g[d] + b[d]);
  }
}

// ---------------------------------------------------------------------------
// GEMM 256x256 (proj, r5 best ~714 TF): counted-vmcnt, 16 waves,
// operand-swapped MFMA -> coalesced float4 C stores.
// ---------------------------------------------------------------------------
__global__ __launch_bounds__(1024) void gemm256_k(
    const bf16* __restrict__ A, const bf16* __restrict__ Bt,
    const float* __restrict__ bias, float* __restrict__ C,
    int M, int N, int K)
{
  __shared__ __align__(16) bf16 As[2][256 * 64];
  __shared__ __align__(16) bf16 Bs[2][256 * 64];

  const int nwg = gridDim.x;
  const int orig = blockIdx.x;
  const int q8 = nwg >> 3, r8 = nwg & 7;
  const int xcd = orig & 7, loc = orig >> 3;
  const int wg = (xcd < r8 ? xcd * (q8 + 1) : r8 * (q8 + 1) + (xcd - r8) * q8) + loc;
  const int nrowt = M >> 8;
  const int rowt = wg & (nrowt - 1);
  const int colt = wg / nrowt;
  const int m0 = rowt * 256;
  const int n0 = colt * 256;
  const int nt = K >> 6;

  const int tid = threadIdx.x;
  const int lane = tid & 63;
  const int wbase = tid & ~63;
  const int wid = tid >> 6;
  const int wm = wid >> 2, wn = wid & 3;
  const int qr = lane & 15, grp = lane >> 4;

  f32x4 acc[4][4];
#pragma unroll
  for (int i = 0; i < 4; ++i)
#pragma unroll
    for (int j = 0; j < 4; ++j) acc[i][j] = (f32x4){0.f, 0.f, 0.f, 0.f};

  auto stage = [&](int bufi, int kt) {
#pragma unroll
    for (int it = 0; it < 2; ++it) {
      const int idx = it * 1024 + tid;
      const int row = idx >> 3, c = idx & 7;
      const int bo = (c * 16) ^ ((row & 7) << 4);
      gl_lds16((const char*)(A + (size_t)(m0 + row) * K + kt) + bo,
               (char*)&As[bufi][0] + (size_t)(it * 1024 + wbase) * 16);
    }
#pragma unroll
    for (int it = 0; it < 2; ++it) {
      const int idx = it * 1024 + tid;
      const int row = idx >> 3, c = idx & 7;
      const int bo = (c * 16) ^ ((row & 7) << 4);
      gl_lds16((const char*)(Bt + (size_t)(n0 + row) * K + kt) + bo,
               (char*)&Bs[bufi][0] + (size_t)(it * 1024 + wbase) * 16);
    }
  };

  stage(0, 0);
  for (int t = 0; t < nt; ++t) {
    const int cur = t & 1;
    if (t + 1 < nt) {
      stage(cur ^ 1, (t + 1) * 64);
      asm volatile("s_waitcnt vmcnt(4)" ::: "memory");
    } else {
      asm volatile("s_waitcnt vmcnt(0)" ::: "memory");
    }
    __builtin_amdgcn_s_barrier();
    asm volatile("" ::: "memory");
#pragma unroll
    for (int ks = 0; ks < 2; ++ks) {
      bf16x8 af[4], bfr[4];
#pragma unroll
      for (int mi = 0; mi < 4; ++mi) {
        const int arow = wm * 64 + mi * 16 + qr;
        const int ab = arow * 128 + ((grp * 16 + ks * 64) ^ ((arow & 7) << 4));
        af[mi] = *(const bf16x8*)((const char*)&As[cur][0] + ab);
      }
#pragma unroll
      for (int ni = 0; ni < 4; ++ni) {
        const int brow = wn * 64 + ni * 16 + qr;
        const int bb = brow * 128 + ((grp * 16 + ks * 64) ^ ((brow & 7) << 4));
        bfr[ni] = *(const bf16x8*)((const char*)&Bs[cur][0] + bb);
      }
      __builtin_amdgcn_s_setprio(1);
#pragma unroll
      for (int mi = 0; mi < 4; ++mi)
#pragma unroll
        for (int ni = 0; ni < 4; ++ni)
          acc[mi][ni] = __builtin_amdgcn_mfma_f32_16x16x32_bf16(
              bfr[ni], af[mi], acc[mi][ni], 0, 0, 0);  // swapped: rows<->n
      __builtin_amdgcn_s_setprio(0);
    }
    __builtin_amdgcn_s_barrier();
    asm volatile("" ::: "memory");
  }

#pragma unroll
  for (int mi = 0; mi < 4; ++mi) {
    const int rowg = m0 + wm * 64 + mi * 16 + qr;
#pragma unroll
    for (int ni = 0; ni < 4; ++ni) {
      const int colg = n0 + wn * 64 + ni * 16 + grp * 4;
      float4 bv = *(const float4*)(bias + colg);
      float4 o;
      o.x = acc[mi][ni][0] + bv.x;
      o.y = acc[mi][ni][1] + bv.y;
      o.z = acc[mi][ni][2] + bv.z;
      o.w = acc[mi][ni][3] + bv.w;
      *(float4*)(C + (size_t)rowg * N + colg) = o;
    }
  }
}

// ---------------------------------------------------------------------------
// GEMM (layer GEMMs): 128x128 tile, BK=64, 8 waves (512 thr), dbuf,
// counted-vmcnt (4 loads/thread/tile -> vmcnt(4) = full-iteration cover).
// MODE 1: C=bf16 relu(acc+bias)    MODE 2: Hacc += acc (atomic if NSPLIT>1)
// MODE 3: Hacc += acc+bias (atomic, bias on split 0)
// MODE 5: QKV split: cols->q,k,Vt^T
// ---------------------------------------------------------------------------
template<int MODE, int NSPLIT>
__global__ __launch_bounds__(512) void gemm8_k(
    const bf16* __restrict__ A, const bf16* __restrict__ Bt,
    const float* __restrict__ bias, void* __restrict__ Cout,
    float* __restrict__ Hacc, bf16* __restrict__ Vt,
    int M, int N, int K)
{
  __shared__ __align__(16) bf16 As[2][128 * 64];
  __shared__ __align__(16) bf16 Bs[2][128 * 64];

  const int nwg = gridDim.x;
  const int orig = blockIdx.x;
  const int q8 = nwg >> 3, r8 = nwg & 7;
  const int xcd = orig & 7, loc = orig >> 3;
  const int wg = (xcd < r8 ? xcd * (q8 + 1) : r8 * (q8 + 1) + (xcd - r8) * q8) + loc;
  const int nrowt = M >> 7;
  const int ntiles = nrowt * (N >> 7);
  const int split = (NSPLIT > 1) ? (wg / ntiles) : 0;
  const int tile  = (NSPLIT > 1) ? (wg % ntiles) : wg;
  const int rowt = tile & (nrowt - 1);
  const int colt = tile / nrowt;
  const int m0 = rowt * 128;
  const int n0 = colt * 128;
  const int Ks = K / NSPLIT;
  const int k_begin = split * Ks;
  const int nt = Ks >> 6;

  const int tid = threadIdx.x;
  const int lane = tid & 63;
  const int wbase = tid & ~63;
  const int wid = tid >> 6;
  const int wm = wid >> 2;
  const int wn = wid & 3;
  const int qr = lane & 15, grp = lane >> 4;

  f32x4 acc[4][2];
#pragma unroll
  for (int i = 0; i < 4; ++i)
#pragma unroll
    for (int j = 0; j < 2; ++j) acc[i][j] = (f32x4){0.f, 0.f, 0.f, 0.f};

  auto stage = [&](int bufi, int kt) {
#pragma unroll
    for (int it = 0; it < 2; ++it) {
      const int idx = it * 512 + tid;
      const int row = idx >> 3, c = idx & 7;
      const int bo = (c * 16) ^ ((row & 7) << 4);
      gl_lds16((const char*)(A + (size_t)(m0 + row) * K + kt) + bo,
               (char*)&As[bufi][0] + (size_t)(it * 512 + wbase) * 16);
    }
#pragma unroll
    for (int it = 0; it < 2; ++it) {
      const int idx = it * 512 + tid;
      const int row = idx >> 3, c = idx & 7;
      const int bo = (c * 16) ^ ((row & 7) << 4);
      gl_lds16((const char*)(Bt + (size_t)(n0 + row) * K + kt) + bo,
               (char*)&Bs[bufi][0] + (size_t)(it * 512 + wbase) * 16);
    }
  };

  stage(0, k_begin);
  for (int t = 0; t < nt; ++t) {
    const int cur = t & 1;
    if (t + 1 < nt) {
      stage(cur ^ 1, k_begin + (t + 1) * 64);
      asm volatile("s_waitcnt vmcnt(4)" ::: "memory");
    } else {
      asm volatile("s_waitcnt vmcnt(0)" ::: "memory");
    }
    __builtin_amdgcn_s_barrier();
    asm volatile("" ::: "memory");
#pragma unroll
    for (int ks = 0; ks < 2; ++ks) {
      bf16x8 af[4], bfr[2];
#pragma unroll
      for (int mi = 0; mi < 4; ++mi) {
        const int arow = wm * 64 + mi * 16 + qr;
        const int ab = arow * 128 + ((grp * 16 + ks * 64) ^ ((arow & 7) << 4));
        af[mi] = *(const bf16x8*)((const char*)&As[cur][0] + ab);
      }
#pragma unroll
      for (int ni = 0; ni < 2; ++ni) {
        const int brow = wn * 32 + ni * 16 + qr;
        const int bb = brow * 128 + ((grp * 16 + ks * 64) ^ ((brow & 7) << 4));
        bfr[ni] = *(const bf16x8*)((const char*)&Bs[cur][0] + bb);
      }
      __builtin_amdgcn_s_setprio(1);
#pragma unroll
      for (int mi = 0; mi < 4; ++mi)
#pragma unroll
        for (int ni = 0; ni < 2; ++ni)
          acc[mi][ni] = __builtin_amdgcn_mfma_f32_16x16x32_bf16(
              af[mi], bfr[ni], acc[mi][ni], 0, 0, 0);
      __builtin_amdgcn_s_setprio(0);
    }
    __builtin_amdgcn_s_barrier();
    asm volatile("" ::: "memory");
  }

  const int sel = (MODE == 5) ? (n0 >> 10) : 0;
#pragma unroll
  for (int ni = 0; ni < 2; ++ni) {
    const int coln = wn * 32 + ni * 16 + qr;
    const int colg = n0 + coln;
    float bv = 0.f;
    if (MODE == 1) bv = bias[colg];
    if (MODE == 3 && split == 0) bv = bias[colg];
#pragma unroll
    for (int mi = 0; mi < 4; ++mi) {
      const int rowg0 = m0 + wm * 64 + mi * 16 + grp * 4;
      if (MODE == 5 && sel == 2) {
        const int b = rowg0 >> 10, s = rowg0 & 1023;
        bf16x4 pv;
#pragma unroll
        for (int r = 0; r < 4; ++r) pv[r] = (bf16)acc[mi][ni][r];
        *(bf16x4*)(Vt + (size_t)b * 1024 * 1024 + (size_t)(colg & 1023) * 1024 + s) = pv;
      } else {
#pragma unroll
        for (int r = 0; r < 4; ++r) {
          const int rowg = rowg0 + r;
          float v = acc[mi][ni][r];
          if (MODE == 1) {
            v += bv; v = v > 0.f ? v : 0.f;
            ((bf16*)Cout)[(size_t)rowg * N + colg] = (bf16)v;
          } else if (MODE == 2) {
            if (NSPLIT > 1) atomicAdd(&Hacc[(size_t)rowg * N + colg], v);
            else            Hacc[(size_t)rowg * N + colg] += v;
          } else if (MODE == 3) {
            if (NSPLIT > 1) atomicAdd(&Hacc[(size_t)rowg * N + colg], v + bv);
            else            Hacc[(size_t)rowg * N + colg] += v + bv;
          } else if (MODE == 5) {
            bf16* cb = (bf16*)Cout + (size_t)sel * 2048 * 1024;
            cb[(size_t)rowg * 1024 + (colg & 1023)] = (bf16)v;
          }
        }
      }
    }
  }
}

// ---------------------------------------------------------------------------
// Flash attention: 4 q-tile waves per block (256 thr), one (b,h,4-qt group)
// per block -> the 4 waves share every K/V tile read via L1 (per-tile slice
// is 2 KB). Per-wave algorithm identical to round-7/8 (4-wide kv groups,
// log2-domain softmax, defer-max).
// ---------------------------------------------------------------------------
__global__ __launch_bounds__(256) void attn_k(const bf16* __restrict__ qm,
    const bf16* __restrict__ km, const bf16* __restrict__ vt,
    bf16* __restrict__ om)
{
  const int tid = threadIdx.x;
  const int lane = tid & 63;
  const int wave = tid >> 6;
  const int qr = lane & 15, g = lane >> 4;
  const int qt = (blockIdx.x & 15) * 4 + wave;
  const int hh = (blockIdx.x >> 4) & 15;
  const int bb = blockIdx.x >> 8;
  const size_t rowb = (size_t)bb * 1024;
  const int hb = hh * 64;

  const bf16* qp = qm + (rowb + qt * 16 + qr) * 1024 + hb + g * 8;
  const bf16x8 qf0 = *(const bf16x8*)qp;
  const bf16x8 qf1 = *(const bf16x8*)(qp + 32);

  const float SC = 0.125f * 1.4426950408889634f;

  float m_run = -1e30f, l_run = 0.f;
  f32x4 oacc[4];
#pragma unroll
  for (int dt = 0; dt < 4; ++dt) oacc[dt] = (f32x4){0.f, 0.f, 0.f, 0.f};

  const int qglob = qt * 16 + qr;
  const bf16* vtb = vt + (size_t)bb * 1024 * 1024;
  const bf16* kbase = km + rowb * 1024 + hb;

  auto tile_step = [&](int kvt, bool masked) {
    const bf16* kp = kbase + (size_t)kvt * 16 * 1024 + qr * 1024 + g * 8;
    bf16x8 kf0 = *(const bf16x8*)kp;
    bf16x8 kf1 = *(const bf16x8*)(kp + 32);
    bf16x4 vf[4];
#pragma unroll
    for (int dt = 0; dt < 4; ++dt)
      vf[dt] = *(const bf16x4*)(vtb + (size_t)(hb + dt * 16 + qr) * 1024 + kvt * 16 + g * 4);
    f32x4 st = (f32x4){0.f, 0.f, 0.f, 0.f};
    st = __builtin_amdgcn_mfma_f32_16x16x32_bf16(kf0, qf0, st, 0, 0, 0);
    st = __builtin_amdgcn_mfma_f32_16x16x32_bf16(kf1, qf1, st, 0, 0, 0);
    float sc[4];
#pragma unroll
    for (int r = 0; r < 4; ++r) {
      sc[r] = st[r] * SC;
      if (masked && (kvt * 16 + g * 4 + r > qglob)) sc[r] = -1e30f;
    }
    float mloc = fmaxf(fmaxf(sc[0], sc[1]), fmaxf(sc[2], sc[3]));
    mloc = fmaxf(mloc, __shfl_xor(mloc, 16));
    mloc = fmaxf(mloc, __shfl_xor(mloc, 32));
    float m_new = fmaxf(m_run, mloc);
    float alpha = exp2f(m_run - m_new);
    float p[4], ps = 0.f;
#pragma unroll
    for (int r = 0; r < 4; ++r) { p[r] = exp2f(sc[r] - m_new); ps += p[r]; }
    ps += __shfl_xor(ps, 16);
    ps += __shfl_xor(ps, 32);
    l_run = l_run * alpha + ps;
    m_run = m_new;
    short4v pfa;
#pragma unroll
    for (int r = 0; r < 4; ++r) pfa[r] = f2bs(p[r]);
#pragma unroll
    for (int dt = 0; dt < 4; ++dt) {
      oacc[dt] *= alpha;
      oacc[dt] = __builtin_amdgcn_mfma_f32_16x16x16bf16_1k(
          __builtin_bit_cast(short4v, vf[dt]), pfa, oacc[dt], 0, 0, 0);
    }
  };

  const int nun = qt;
  int kvt = 0;
  for (; kvt + 3 < nun; kvt += 4) {
    bf16x8 kf[4][2];
#pragma unroll
    for (int tt = 0; tt < 4; ++tt) {
      const bf16* kp = kbase + (size_t)(kvt + tt) * 16 * 1024 + qr * 1024 + g * 8;
      kf[tt][0] = *(const bf16x8*)kp;
      kf[tt][1] = *(const bf16x8*)(kp + 32);
    }
    bf16x4 vf[4][4];
#pragma unroll
    for (int tt = 0; tt < 4; ++tt)
#pragma unroll
      for (int dt = 0; dt < 4; ++dt)
        vf[tt][dt] = *(const bf16x4*)(vtb + (size_t)(hb + dt * 16 + qr) * 1024
                                      + (kvt + tt) * 16 + g * 4);
    f32x4 st[4];
#pragma unroll
    for (int tt = 0; tt < 4; ++tt) {
      st[tt] = (f32x4){0.f, 0.f, 0.f, 0.f};
      st[tt] = __builtin_amdgcn_mfma_f32_16x16x32_bf16(kf[tt][0], qf0, st[tt], 0, 0, 0);
      st[tt] = __builtin_amdgcn_mfma_f32_16x16x32_bf16(kf[tt][1], qf1, st[tt], 0, 0, 0);
    }
    float p[4][4];
    float mloc = -1e30f;
#pragma unroll
    for (int tt = 0; tt < 4; ++tt)
#pragma unroll
      for (int r = 0; r < 4; ++r) {
        p[tt][r] = st[tt][r] * SC;
        mloc = fmaxf(mloc, p[tt][r]);
      }
    mloc = fmaxf(mloc, __shfl_xor(mloc, 16));
    mloc = fmaxf(mloc, __shfl_xor(mloc, 32));
    if (!__all(mloc <= m_run + 8.f)) {
      float m_new = fmaxf(m_run, mloc);
      float alpha = exp2f(m_run - m_new);
      l_run *= alpha;
#pragma unroll
      for (int dt = 0; dt < 4; ++dt) oacc[dt] *= alpha;
      m_run = m_new;
    }
    float ps = 0.f;
#pragma unroll
    for (int tt = 0; tt < 4; ++tt)
#pragma unroll
      for (int r = 0; r < 4; ++r) {
        p[tt][r] = exp2f(p[tt][r] - m_run);
        ps += p[tt][r];
      }
    ps += __shfl_xor(ps, 16);
    ps += __shfl_xor(ps, 32);
    l_run += ps;
    short4v pf[4];
#pragma unroll
    for (int tt = 0; tt < 4; ++tt)
#pragma unroll
      for (int r = 0; r < 4; ++r) pf[tt][r] = f2bs(p[tt][r]);
#pragma unroll
    for (int dt = 0; dt < 4; ++dt)
#pragma unroll
      for (int tt = 0; tt < 4; ++tt)
        oacc[dt] = __builtin_amdgcn_mfma_f32_16x16x16bf16_1k(
            __builtin_bit_cast(short4v, vf[tt][dt]), pf[tt], oacc[dt], 0, 0, 0);
  }
  for (; kvt < nun; ++kvt) tile_step(kvt, false);
  tile_step(qt, true);

  const float inv = 1.f / l_run;
  bf16* op = om + (rowb + qt * 16 + qr) * 1024 + hb;
#pragma unroll
  for (int dt = 0; dt < 4; ++dt)
#pragma unroll
    for (int r = 0; r < 4; ++r)
      op[dt * 16 + g * 4 + r] = (bf16)(oacc[dt][r] * inv);
}

// ---------------------------------------------------------------------------
extern "C" void kernel_launch(void* const* d_in, const int* in_sizes, int n_in,
                              void* d_out, int out_size, void* d_ws, size_t ws_size,
                              hipStream_t stream)
{
  (void)in_sizes; (void)n_in; (void)out_size; (void)ws_size;
  const int*   x     = (const int*)d_in[0];
  const float* emb   = (const float*)d_in[2];
  const float* Wq    = (const float*)d_in[3];
  const float* Wk    = (const float*)d_in[4];
  const float* Wv    = (const float*)d_in[5];
  const float* Wo    = (const float*)d_in[6];
  const float* ln1g  = (const float*)d_in[7];
  const float* ln1b  = (const float*)d_in[8];
  const float* ln2g  = (const float*)d_in[9];
  const float* ln2b  = (const float*)d_in[10];
  const float* W1    = (const float*)d_in[11];
  const float* b1    = (const float*)d_in[12];
  const float* W2    = (const float*)d_in[13];
  const float* b2    = (const float*)d_in[14];
  const float* lnfg  = (const float*)d_in[15];
  const float* lnfb  = (const float*)d_in[16];
  const float* projW = (const float*)d_in[17];
  const float* projb = (const float*)d_in[18];

  char* ws = (char*)d_ws;
  const size_t MB = 1u << 20;
  float* h    = (float*)(ws + 0);            // 8 MB
  bf16*  ain  = (bf16*)(ws + 8 * MB);        // 4 MB
  bf16*  qb   = (bf16*)(ws + 12 * MB);       // 4 MB
  bf16*  kb   = (bf16*)(ws + 16 * MB);       // 4 MB
  bf16*  vtb  = (bf16*)(ws + 20 * MB);       // 4 MB (V^T)
  bf16*  ob   = (bf16*)(ws + 24 * MB);       // 4 MB
  bf16*  mid  = (bf16*)(ws + 28 * MB);       // 16 MB
  bf16*  Bqkv = (bf16*)(ws + 44 * MB);       // 48 MB
  bf16*  Bo   = (bf16*)(ws + 92 * MB);       // 16 MB
  bf16*  B1t  = (bf16*)(ws + 108 * MB);      // 64 MB
  bf16*  B2t  = (bf16*)(ws + 172 * MB);      // 64 MB
  bf16*  Bprj = (bf16*)(ws + 236 * MB);      // 65.5 MB

  const long M1 = 1024 * 1024, M3 = 3 * M1, M4 = 4 * M1;

  wtall_k<<<dim3(65152), 256, 0, stream>>>(Wq, Wk, Wv, Wo, W1, W2, projW,
                                           Bqkv, Bo, B1t, B2t, Bprj);

  embed_k<<<dim3(2048), 256, 0, stream>>>(x, emb, h);
  for (int i = 0; i < 8; ++i) {
    ln_k<<<dim3(2048), 256, 0, stream>>>(h, ln1g + i * 1024, ln1b + i * 1024, ain);
    gemm8_k<5,1><<<dim3(384), 512, 0, stream>>>(ain, Bqkv + i * M3, nullptr,
                                                qb, nullptr, vtb, 2048, 3072, 1024);
    attn_k<<<dim3(512), 256, 0, stream>>>(qb, kb, vtb, ob);
    gemm8_k<2,2><<<dim3(256), 512, 0, stream>>>(ob, Bo + i * M1, nullptr,
                                                nullptr, h, nullptr, 2048, 1024, 1024);
    ln_k<<<dim3(2048), 256, 0, stream>>>(h, ln2g + i * 1024, ln2b + i * 1024, ain);
    gemm8_k<1,1><<<dim3(512), 512, 0, stream>>>(ain, B1t + i * M4, b1 + i * 4096,
                                                mid, nullptr, nullptr, 2048, 4096, 1024);
    gemm8_k<3,2><<<dim3(256), 512, 0, stream>>>(mid, B2t + i * M4, b2 + i * 1024,
                                                nullptr, h, nullptr, 2048, 1024, 4096);
  }
  ln_k<<<dim3(2048), 256, 0, stream>>>(h, lnfg, lnfb, ain);
  gemm256_k<<<dim3(1000), 1024, 0, stream>>>(ain, Bprj, projb,
                                             (float*)d_out, 2048, 32000, 1024);
}

// Round 12
// 2077.250 us; speedup vs baseline: 1.0439x; 1.0036x over previous
//
#include <hip/hip_runtime.h>

typedef __bf16 bf16;
typedef __bf16 bf16x4 __attribute__((ext_vector_type(4)));
typedef __bf16 bf16x8 __attribute__((ext_vector_type(8)));
typedef float f32x4 __attribute__((ext_vector_type(4)));
typedef short short4v __attribute__((ext_vector_type(4)));

__device__ __forceinline__ short f2bs(float x) {
  bf16 hv = (bf16)x;
  return __builtin_bit_cast(short, hv);
}

__device__ __forceinline__ void gl_lds16(const void* g, void* l) {
  __builtin_amdgcn_global_load_lds(
      (const __attribute__((address_space(1))) unsigned int*)g,
      (__attribute__((address_space(3))) unsigned int*)l, 16, 0, 0);
}

// ---------------------------------------------------------------------------
// Merged weight pre-pass v3: fp32 [K][N] -> bf16 [N][K], ALL weights, one
// launch. 64k x 64n tile per block (256 B read granule per row), two
// [64][33] LDS sub-tiles (stride-33 keeps reads 2-way-conflict-free).
// Region decode (64x64 tiles):
//   [0,8192)       square weights {Wq,Wk,Wv,Wo} x 8 layers (1024x1024)
//   [8192,16384)   W1  [8] 1024x4096
//   [16384,24576)  W2  [8] 4096x1024
//   [24576,32576)  proj 1024x32000
// ---------------------------------------------------------------------------
__global__ __launch_bounds__(256) void wtall_k(
    const float* __restrict__ Wq, const float* __restrict__ Wk,
    const float* __restrict__ Wv, const float* __restrict__ Wo,
    const float* __restrict__ W1, const float* __restrict__ W2,
    const float* __restrict__ Pw,
    bf16* __restrict__ Bqkv, bf16* __restrict__ Bo,
    bf16* __restrict__ B1t, bf16* __restrict__ B2t, bf16* __restrict__ Bprj)
{
  __shared__ float ta[64][33], tb[64][33];
  const long M1 = 1024 * 1024, M3 = 3 * M1, M4 = 4 * M1;
  int b = blockIdx.x;
  const float* ip; bf16* op; int K, N, n0, k0;
  if (b < 8192) {
    const int x = b & 15, y = (b >> 4) & 15, z = b >> 8;
    const int which = z >> 3, layer = z & 7;
    ip = (which == 0 ? Wq : which == 1 ? Wk : which == 2 ? Wv : Wo)
         + (size_t)layer * M1;
    op = (which < 3) ? (Bqkv + (size_t)layer * M3 + (size_t)which * M1)
                     : (Bo + (size_t)layer * M1);
    K = 1024; N = 1024; n0 = x * 64; k0 = y * 64;
  } else if (b < 16384) {
    b -= 8192;
    const int x = b & 63, y = (b >> 6) & 15, z = b >> 10;
    ip = W1 + (size_t)z * M4; op = B1t + (size_t)z * M4;
    K = 1024; N = 4096; n0 = x * 64; k0 = y * 64;
  } else if (b < 24576) {
    b -= 16384;
    const int x = b & 15, y = (b >> 4) & 63, z = b >> 10;
    ip = W2 + (size_t)z * M4; op = B2t + (size_t)z * M4;
    K = 4096; N = 1024; n0 = x * 64; k0 = y * 64;
  } else {
    b -= 24576;
    const int x = b % 500, y = b / 500;
    ip = Pw; op = Bprj;
    K = 1024; N = 32000; n0 = x * 64; k0 = y * 64;
  }
  const int tid = threadIdx.x;
  const int kr = tid >> 3, nc = (tid & 7) * 4;
  // loads: rows kr, kr+32; cols [n0, n0+64) split into two 32-col sub-tiles
#pragma unroll
  for (int hh = 0; hh < 2; ++hh) {
    const float* rp = ip + (size_t)(k0 + kr + hh * 32) * N + n0;
    float4 va = *(const float4*)(rp + nc);
    float4 vb = *(const float4*)(rp + 32 + nc);
    ta[kr + hh * 32][nc]     = va.x;
    ta[kr + hh * 32][nc + 1] = va.y;
    ta[kr + hh * 32][nc + 2] = va.z;
    ta[kr + hh * 32][nc + 3] = va.w;
    tb[kr + hh * 32][nc]     = vb.x;
    tb[kr + hh * 32][nc + 1] = vb.y;
    tb[kr + hh * 32][nc + 2] = vb.z;
    tb[kr + hh * 32][nc + 3] = vb.w;
  }
  __syncthreads();
  const int nr = tid >> 3, kc = (tid & 7) * 8;
  bf16x8 oa, ob;
#pragma unroll
  for (int j = 0; j < 8; ++j) { oa[j] = (bf16)ta[kc + j][nr]; ob[j] = (bf16)tb[kc + j][nr]; }
  *(bf16x8*)(op + (size_t)(n0 + nr) * K + k0 + kc) = oa;
  *(bf16x8*)(op + (size_t)(n0 + 32 + nr) * K + k0 + kc) = ob;
}

// ---------------------------------------------------------------------------
// Embedding: h[m][d] = emb[x[m]][d]*32 + PE(s,d)
// ---------------------------------------------------------------------------
__global__ __launch_bounds__(256) void embed_k(const int* __restrict__ x,
    const float* __restrict__ emb, float* __restrict__ h)
{
  const int m = blockIdx.x, t = threadIdx.x;
  const int s = m & 1023;
  const int tok = x[m];
  const int d0 = t * 4;
  float4 e = *(const float4*)(emb + (size_t)tok * 1024 + d0);
  const float* ep = &e.x;
  float r[4];
#pragma unroll
  for (int j = 0; j < 4; ++j) {
    int d = d0 + j;
    float freq = expf((float)(d & ~1) * (-9.2103403719761836f / 1024.f));
    float ang = (float)s * freq;
    float pe = (d & 1) ? cosf(ang) : sinf(ang);
    r[j] = ep[j] * 32.f + pe;
  }
  *(float4*)(h + (size_t)m * 1024 + d0) = make_float4(r[0], r[1], r[2], r[3]);
}

// ---------------------------------------------------------------------------
// LayerNorm (fp32 in, bf16 out), one block per row of 1024
// ---------------------------------------------------------------------------
__global__ __launch_bounds__(256) void ln_k(const float* __restrict__ h,
    const float* __restrict__ g, const float* __restrict__ b,
    bf16* __restrict__ out)
{
  const int row = blockIdx.x, t = threadIdx.x;
  const float* hr = h + (size_t)row * 1024;
  float4 x = *(const float4*)(hr + t * 4);
  float s  = x.x + x.y + x.z + x.w;
  float ss = x.x * x.x + x.y * x.y + x.z * x.z + x.w * x.w;
#pragma unroll
  for (int off = 32; off >= 1; off >>= 1) {
    s  += __shfl_down(s, off);
    ss += __shfl_down(ss, off);
  }
  __shared__ float sb[4], ssb[4];
  if ((t & 63) == 0) { sb[t >> 6] = s; ssb[t >> 6] = ss; }
  __syncthreads();
  s  = sb[0] + sb[1] + sb[2] + sb[3];
  ss = ssb[0] + ssb[1] + ssb[2] + ssb[3];
  const float mean = s * (1.f / 1024.f);
  const float var  = ss * (1.f / 1024.f) - mean * mean;
  const float rstd = rsqrtf(var + 1e-5f);
  const float* xp = &x.x;
#pragma unroll
  for (int j = 0; j < 4; ++j) {
    int d = t * 4 + j;
    out[(size_t)row * 1024 + d] = (bf16)((xp[j] - mean) * rstd * g[d] + b[d]);
  }
}

// ---------------------------------------------------------------------------
// GEMM 256x256 (proj, r5 best ~714 TF): counted-vmcnt, 16 waves,
// operand-swapped MFMA -> coalesced float4 C stores.
// ---------------------------------------------------------------------------
__global__ __launch_bounds__(1024) void gemm256_k(
    const bf16* __restrict__ A, const bf16* __restrict__ Bt,
    const float* __restrict__ bias, float* __restrict__ C,
    int M, int N, int K)
{
  __shared__ __align__(16) bf16 As[2][256 * 64];
  __shared__ __align__(16) bf16 Bs[2][256 * 64];

  const int nwg = gridDim.x;
  const int orig = blockIdx.x;
  const int q8 = nwg >> 3, r8 = nwg & 7;
  const int xcd = orig & 7, loc = orig >> 3;
  const int wg = (xcd < r8 ? xcd * (q8 + 1) : r8 * (q8 + 1) + (xcd - r8) * q8) + loc;
  const int nrowt = M >> 8;
  const int rowt = wg & (nrowt - 1);
  const int colt = wg / nrowt;
  const int m0 = rowt * 256;
  const int n0 = colt * 256;
  const int nt = K >> 6;

  const int tid = threadIdx.x;
  const int lane = tid & 63;
  const int wbase = tid & ~63;
  const int wid = tid >> 6;
  const int wm = wid >> 2, wn = wid & 3;
  const int qr = lane & 15, grp = lane >> 4;

  f32x4 acc[4][4];
#pragma unroll
  for (int i = 0; i < 4; ++i)
#pragma unroll
    for (int j = 0; j < 4; ++j) acc[i][j] = (f32x4){0.f, 0.f, 0.f, 0.f};

  auto stage = [&](int bufi, int kt) {
#pragma unroll
    for (int it = 0; it < 2; ++it) {
      const int idx = it * 1024 + tid;
      const int row = idx >> 3, c = idx & 7;
      const int bo = (c * 16) ^ ((row & 7) << 4);
      gl_lds16((const char*)(A + (size_t)(m0 + row) * K + kt) + bo,
               (char*)&As[bufi][0] + (size_t)(it * 1024 + wbase) * 16);
    }
#pragma unroll
    for (int it = 0; it < 2; ++it) {
      const int idx = it * 1024 + tid;
      const int row = idx >> 3, c = idx & 7;
      const int bo = (c * 16) ^ ((row & 7) << 4);
      gl_lds16((const char*)(Bt + (size_t)(n0 + row) * K + kt) + bo,
               (char*)&Bs[bufi][0] + (size_t)(it * 1024 + wbase) * 16);
    }
  };

  stage(0, 0);
  for (int t = 0; t < nt; ++t) {
    const int cur = t & 1;
    if (t + 1 < nt) {
      stage(cur ^ 1, (t + 1) * 64);
      asm volatile("s_waitcnt vmcnt(4)" ::: "memory");
    } else {
      asm volatile("s_waitcnt vmcnt(0)" ::: "memory");
    }
    __builtin_amdgcn_s_barrier();
    asm volatile("" ::: "memory");
#pragma unroll
    for (int ks = 0; ks < 2; ++ks) {
      bf16x8 af[4], bfr[4];
#pragma unroll
      for (int mi = 0; mi < 4; ++mi) {
        const int arow = wm * 64 + mi * 16 + qr;
        const int ab = arow * 128 + ((grp * 16 + ks * 64) ^ ((arow & 7) << 4));
        af[mi] = *(const bf16x8*)((const char*)&As[cur][0] + ab);
      }
#pragma unroll
      for (int ni = 0; ni < 4; ++ni) {
        const int brow = wn * 64 + ni * 16 + qr;
        const int bb = brow * 128 + ((grp * 16 + ks * 64) ^ ((brow & 7) << 4));
        bfr[ni] = *(const bf16x8*)((const char*)&Bs[cur][0] + bb);
      }
      __builtin_amdgcn_s_setprio(1);
#pragma unroll
      for (int mi = 0; mi < 4; ++mi)
#pragma unroll
        for (int ni = 0; ni < 4; ++ni)
          acc[mi][ni] = __builtin_amdgcn_mfma_f32_16x16x32_bf16(
              bfr[ni], af[mi], acc[mi][ni], 0, 0, 0);  // swapped: rows<->n
      __builtin_amdgcn_s_setprio(0);
    }
    __builtin_amdgcn_s_barrier();
    asm volatile("" ::: "memory");
  }

#pragma unroll
  for (int mi = 0; mi < 4; ++mi) {
    const int rowg = m0 + wm * 64 + mi * 16 + qr;
#pragma unroll
    for (int ni = 0; ni < 4; ++ni) {
      const int colg = n0 + wn * 64 + ni * 16 + grp * 4;
      float4 bv = *(const float4*)(bias + colg);
      float4 o;
      o.x = acc[mi][ni][0] + bv.x;
      o.y = acc[mi][ni][1] + bv.y;
      o.z = acc[mi][ni][2] + bv.z;
      o.w = acc[mi][ni][3] + bv.w;
      *(float4*)(C + (size_t)rowg * N + colg) = o;
    }
  }
}

// ---------------------------------------------------------------------------
// GEMM (layer GEMMs): 128x128 tile, BK=64, 8 waves (512 thr), dbuf,
// counted-vmcnt (4 loads/thread/tile -> vmcnt(4) = full-iteration cover).
// MODE 1: C=bf16 relu(acc+bias)    MODE 2: Hacc += acc (atomic if NSPLIT>1)
// MODE 3: Hacc += acc+bias (atomic, bias on split 0)
// MODE 5: QKV split: cols->q,k,Vt^T
// ---------------------------------------------------------------------------
template<int MODE, int NSPLIT>
__global__ __launch_bounds__(512) void gemm8_k(
    const bf16* __restrict__ A, const bf16* __restrict__ Bt,
    const float* __restrict__ bias, void* __restrict__ Cout,
    float* __restrict__ Hacc, bf16* __restrict__ Vt,
    int M, int N, int K)
{
  __shared__ __align__(16) bf16 As[2][128 * 64];
  __shared__ __align__(16) bf16 Bs[2][128 * 64];

  const int nwg = gridDim.x;
  const int orig = blockIdx.x;
  const int q8 = nwg >> 3, r8 = nwg & 7;
  const int xcd = orig & 7, loc = orig >> 3;
  const int wg = (xcd < r8 ? xcd * (q8 + 1) : r8 * (q8 + 1) + (xcd - r8) * q8) + loc;
  const int nrowt = M >> 7;
  const int ntiles = nrowt * (N >> 7);
  const int split = (NSPLIT > 1) ? (wg / ntiles) : 0;
  const int tile  = (NSPLIT > 1) ? (wg % ntiles) : wg;
  const int rowt = tile & (nrowt - 1);
  const int colt = tile / nrowt;
  const int m0 = rowt * 128;
  const int n0 = colt * 128;
  const int Ks = K / NSPLIT;
  const int k_begin = split * Ks;
  const int nt = Ks >> 6;

  const int tid = threadIdx.x;
  const int lane = tid & 63;
  const int wbase = tid & ~63;
  const int wid = tid >> 6;
  const int wm = wid >> 2;
  const int wn = wid & 3;
  const int qr = lane & 15, grp = lane >> 4;

  f32x4 acc[4][2];
#pragma unroll
  for (int i = 0; i < 4; ++i)
#pragma unroll
    for (int j = 0; j < 2; ++j) acc[i][j] = (f32x4){0.f, 0.f, 0.f, 0.f};

  auto stage = [&](int bufi, int kt) {
#pragma unroll
    for (int it = 0; it < 2; ++it) {
      const int idx = it * 512 + tid;
      const int row = idx >> 3, c = idx & 7;
      const int bo = (c * 16) ^ ((row & 7) << 4);
      gl_lds16((const char*)(A + (size_t)(m0 + row) * K + kt) + bo,
               (char*)&As[bufi][0] + (size_t)(it * 512 + wbase) * 16);
    }
#pragma unroll
    for (int it = 0; it < 2; ++it) {
      const int idx = it * 512 + tid;
      const int row = idx >> 3, c = idx & 7;
      const int bo = (c * 16) ^ ((row & 7) << 4);
      gl_lds16((const char*)(Bt + (size_t)(n0 + row) * K + kt) + bo,
               (char*)&Bs[bufi][0] + (size_t)(it * 512 + wbase) * 16);
    }
  };

  stage(0, k_begin);
  for (int t = 0; t < nt; ++t) {
    const int cur = t & 1;
    if (t + 1 < nt) {
      stage(cur ^ 1, k_begin + (t + 1) * 64);
      asm volatile("s_waitcnt vmcnt(4)" ::: "memory");
    } else {
      asm volatile("s_waitcnt vmcnt(0)" ::: "memory");
    }
    __builtin_amdgcn_s_barrier();
    asm volatile("" ::: "memory");
#pragma unroll
    for (int ks = 0; ks < 2; ++ks) {
      bf16x8 af[4], bfr[2];
#pragma unroll
      for (int mi = 0; mi < 4; ++mi) {
        const int arow = wm * 64 + mi * 16 + qr;
        const int ab = arow * 128 + ((grp * 16 + ks * 64) ^ ((arow & 7) << 4));
        af[mi] = *(const bf16x8*)((const char*)&As[cur][0] + ab);
      }
#pragma unroll
      for (int ni = 0; ni < 2; ++ni) {
        const int brow = wn * 32 + ni * 16 + qr;
        const int bb = brow * 128 + ((grp * 16 + ks * 64) ^ ((brow & 7) << 4));
        bfr[ni] = *(const bf16x8*)((const char*)&Bs[cur][0] + bb);
      }
      __builtin_amdgcn_s_setprio(1);
#pragma unroll
      for (int mi = 0; mi < 4; ++mi)
#pragma unroll
        for (int ni = 0; ni < 2; ++ni)
          acc[mi][ni] = __builtin_amdgcn_mfma_f32_16x16x32_bf16(
              af[mi], bfr[ni], acc[mi][ni], 0, 0, 0);
      __builtin_amdgcn_s_setprio(0);
    }
    __builtin_amdgcn_s_barrier();
    asm volatile("" ::: "memory");
  }

  const int sel = (MODE == 5) ? (n0 >> 10) : 0;
#pragma unroll
  for (int ni = 0; ni < 2; ++ni) {
    const int coln = wn * 32 + ni * 16 + qr;
    const int colg = n0 + coln;
    float bv = 0.f;
    if (MODE == 1) bv = bias[colg];
    if (MODE == 3 && split == 0) bv = bias[colg];
#pragma unroll
    for (int mi = 0; mi < 4; ++mi) {
      const int rowg0 = m0 + wm * 64 + mi * 16 + grp * 4;
      if (MODE == 5 && sel == 2) {
        const int b = rowg0 >> 10, s = rowg0 & 1023;
        bf16x4 pv;
#pragma unroll
        for (int r = 0; r < 4; ++r) pv[r] = (bf16)acc[mi][ni][r];
        *(bf16x4*)(Vt + (size_t)b * 1024 * 1024 + (size_t)(colg & 1023) * 1024 + s) = pv;
      } else {
#pragma unroll
        for (int r = 0; r < 4; ++r) {
          const int rowg = rowg0 + r;
          float v = acc[mi][ni][r];
          if (MODE == 1) {
            v += bv; v = v > 0.f ? v : 0.f;
            ((bf16*)Cout)[(size_t)rowg * N + colg] = (bf16)v;
          } else if (MODE == 2) {
            if (NSPLIT > 1) atomicAdd(&Hacc[(size_t)rowg * N + colg], v);
            else            Hacc[(size_t)rowg * N + colg] += v;
          } else if (MODE == 3) {
            if (NSPLIT > 1) atomicAdd(&Hacc[(size_t)rowg * N + colg], v + bv);
            else            Hacc[(size_t)rowg * N + colg] += v + bv;
          } else if (MODE == 5) {
            bf16* cb = (bf16*)Cout + (size_t)sel * 2048 * 1024;
            cb[(size_t)rowg * 1024 + (colg & 1023)] = (bf16)v;
          }
        }
      }
    }
  }
}

// ---------------------------------------------------------------------------
// Flash attention: 4 q-tile waves per block (256 thr); waves of one (b,h)
// share K/V tile reads via L1. 4-wide kv groups, log2 softmax, defer-max.
// ---------------------------------------------------------------------------
__global__ __launch_bounds__(256) void attn_k(const bf16* __restrict__ qm,
    const bf16* __restrict__ km, const bf16* __restrict__ vt,
    bf16* __restrict__ om)
{
  const int tid = threadIdx.x;
  const int lane = tid & 63;
  const int wave = tid >> 6;
  const int qr = lane & 15, g = lane >> 4;
  const int qt = (blockIdx.x & 15) * 4 + wave;
  const int hh = (blockIdx.x >> 4) & 15;
  const int bb = blockIdx.x >> 8;
  const size_t rowb = (size_t)bb * 1024;
  const int hb = hh * 64;

  const bf16* qp = qm + (rowb + qt * 16 + qr) * 1024 + hb + g * 8;
  const bf16x8 qf0 = *(const bf16x8*)qp;
  const bf16x8 qf1 = *(const bf16x8*)(qp + 32);

  const float SC = 0.125f * 1.4426950408889634f;

  float m_run = -1e30f, l_run = 0.f;
  f32x4 oacc[4];
#pragma unroll
  for (int dt = 0; dt < 4; ++dt) oacc[dt] = (f32x4){0.f, 0.f, 0.f, 0.f};

  const int qglob = qt * 16 + qr;
  const bf16* vtb = vt + (size_t)bb * 1024 * 1024;
  const bf16* kbase = km + rowb * 1024 + hb;

  auto tile_step = [&](int kvt, bool masked) {
    const bf16* kp = kbase + (size_t)kvt * 16 * 1024 + qr * 1024 + g * 8;
    bf16x8 kf0 = *(const bf16x8*)kp;
    bf16x8 kf1 = *(const bf16x8*)(kp + 32);
    bf16x4 vf[4];
#pragma unroll
    for (int dt = 0; dt < 4; ++dt)
      vf[dt] = *(const bf16x4*)(vtb + (size_t)(hb + dt * 16 + qr) * 1024 + kvt * 16 + g * 4);
    f32x4 st = (f32x4){0.f, 0.f, 0.f, 0.f};
    st = __builtin_amdgcn_mfma_f32_16x16x32_bf16(kf0, qf0, st, 0, 0, 0);
    st = __builtin_amdgcn_mfma_f32_16x16x32_bf16(kf1, qf1, st, 0, 0, 0);
    float sc[4];
#pragma unroll
    for (int r = 0; r < 4; ++r) {
      sc[r] = st[r] * SC;
      if (masked && (kvt * 16 + g * 4 + r > qglob)) sc[r] = -1e30f;
    }
    float mloc = fmaxf(fmaxf(sc[0], sc[1]), fmaxf(sc[2], sc[3]));
    mloc = fmaxf(mloc, __shfl_xor(mloc, 16));
    mloc = fmaxf(mloc, __shfl_xor(mloc, 32));
    float m_new = fmaxf(m_run, mloc);
    float alpha = exp2f(m_run - m_new);
    float p[4], ps = 0.f;
#pragma unroll
    for (int r = 0; r < 4; ++r) { p[r] = exp2f(sc[r] - m_new); ps += p[r]; }
    ps += __shfl_xor(ps, 16);
    ps += __shfl_xor(ps, 32);
    l_run = l_run * alpha + ps;
    m_run = m_new;
    short4v pfa;
#pragma unroll
    for (int r = 0; r < 4; ++r) pfa[r] = f2bs(p[r]);
#pragma unroll
    for (int dt = 0; dt < 4; ++dt) {
      oacc[dt] *= alpha;
      oacc[dt] = __builtin_amdgcn_mfma_f32_16x16x16bf16_1k(
          __builtin_bit_cast(short4v, vf[dt]), pfa, oacc[dt], 0, 0, 0);
    }
  };

  const int nun = qt;
  int kvt = 0;
  for (; kvt + 3 < nun; kvt += 4) {
    bf16x8 kf[4][2];
#pragma unroll
    for (int tt = 0; tt < 4; ++tt) {
      const bf16* kp = kbase + (size_t)(kvt + tt) * 16 * 1024 + qr * 1024 + g * 8;
      kf[tt][0] = *(const bf16x8*)kp;
      kf[tt][1] = *(const bf16x8*)(kp + 32);
    }
    bf16x4 vf[4][4];
#pragma unroll
    for (int tt = 0; tt < 4; ++tt)
#pragma unroll
      for (int dt = 0; dt < 4; ++dt)
        vf[tt][dt] = *(const bf16x4*)(vtb + (size_t)(hb + dt * 16 + qr) * 1024
                                      + (kvt + tt) * 16 + g * 4);
    f32x4 st[4];
#pragma unroll
    for (int tt = 0; tt < 4; ++tt) {
      st[tt] = (f32x4){0.f, 0.f, 0.f, 0.f};
      st[tt] = __builtin_amdgcn_mfma_f32_16x16x32_bf16(kf[tt][0], qf0, st[tt], 0, 0, 0);
      st[tt] = __builtin_amdgcn_mfma_f32_16x16x32_bf16(kf[tt][1], qf1, st[tt], 0, 0, 0);
    }
    float p[4][4];
    float mloc = -1e30f;
#pragma unroll
    for (int tt = 0; tt < 4; ++tt)
#pragma unroll
      for (int r = 0; r < 4; ++r) {
        p[tt][r] = st[tt][r] * SC;
        mloc = fmaxf(mloc, p[tt][r]);
      }
    mloc = fmaxf(mloc, __shfl_xor(mloc, 16));
    mloc = fmaxf(mloc, __shfl_xor(mloc, 32));
    if (!__all(mloc <= m_run + 8.f)) {
      float m_new = fmaxf(m_run, mloc);
      float alpha = exp2f(m_run - m_new);
      l_run *= alpha;
#pragma unroll
      for (int dt = 0; dt < 4; ++dt) oacc[dt] *= alpha;
      m_run = m_new;
    }
    float ps = 0.f;
#pragma unroll
    for (int tt = 0; tt < 4; ++tt)
#pragma unroll
      for (int r = 0; r < 4; ++r) {
        p[tt][r] = exp2f(p[tt][r] - m_run);
        ps += p[tt][r];
      }
    ps += __shfl_xor(ps, 16);
    ps += __shfl_xor(ps, 32);
    l_run += ps;
    short4v pf[4];
#pragma unroll
    for (int tt = 0; tt < 4; ++tt)
#pragma unroll
      for (int r = 0; r < 4; ++r) pf[tt][r] = f2bs(p[tt][r]);
#pragma unroll
    for (int dt = 0; dt < 4; ++dt)
#pragma unroll
      for (int tt = 0; tt < 4; ++tt)
        oacc[dt] = __builtin_amdgcn_mfma_f32_16x16x16bf16_1k(
            __builtin_bit_cast(short4v, vf[tt][dt]), pf[tt], oacc[dt], 0, 0, 0);
  }
  for (; kvt < nun; ++kvt) tile_step(kvt, false);
  tile_step(qt, true);

  const float inv = 1.f / l_run;
  bf16* op = om + (rowb + qt * 16 + qr) * 1024 + hb;
#pragma unroll
  for (int dt = 0; dt < 4; ++dt)
#pragma unroll
    for (int r = 0; r < 4; ++r)
      op[dt * 16 + g * 4 + r] = (bf16)(oacc[dt][r] * inv);
}

// ---------------------------------------------------------------------------
extern "C" void kernel_launch(void* const* d_in, const int* in_sizes, int n_in,
                              void* d_out, int out_size, void* d_ws, size_t ws_size,
                              hipStream_t stream)
{
  (void)in_sizes; (void)n_in; (void)out_size; (void)ws_size;
  const int*   x     = (const int*)d_in[0];
  const float* emb   = (const float*)d_in[2];
  const float* Wq    = (const float*)d_in[3];
  const float* Wk    = (const float*)d_in[4];
  const float* Wv    = (const float*)d_in[5];
  const float* Wo    = (const float*)d_in[6];
  const float* ln1g  = (const float*)d_in[7];
  const float* ln1b  = (const float*)d_in[8];
  const float* ln2g  = (const float*)d_in[9];
  const float* ln2b  = (const float*)d_in[10];
  const float* W1    = (const float*)d_in[11];
  const float* b1    = (const float*)d_in[12];
  const float* W2    = (const float*)d_in[13];
  const float* b2    = (const float*)d_in[14];
  const float* lnfg  = (const float*)d_in[15];
  const float* lnfb  = (const float*)d_in[16];
  const float* projW = (const float*)d_in[17];
  const float* projb = (const float*)d_in[18];

  char* ws = (char*)d_ws;
  const size_t MB = 1u << 20;
  float* h    = (float*)(ws + 0);            // 8 MB
  bf16*  ain  = (bf16*)(ws + 8 * MB);        // 4 MB
  bf16*  qb   = (bf16*)(ws + 12 * MB);       // 4 MB
  bf16*  kb   = (bf16*)(ws + 16 * MB);       // 4 MB
  bf16*  vtb  = (bf16*)(ws + 20 * MB);       // 4 MB (V^T)
  bf16*  ob   = (bf16*)(ws + 24 * MB);       // 4 MB
  bf16*  mid  = (bf16*)(ws + 28 * MB);       // 16 MB
  bf16*  Bqkv = (bf16*)(ws + 44 * MB);       // 48 MB
  bf16*  Bo   = (bf16*)(ws + 92 * MB);       // 16 MB
  bf16*  B1t  = (bf16*)(ws + 108 * MB);      // 64 MB
  bf16*  B2t  = (bf16*)(ws + 172 * MB);      // 64 MB
  bf16*  Bprj = (bf16*)(ws + 236 * MB);      // 65.5 MB

  const long M1 = 1024 * 1024, M3 = 3 * M1, M4 = 4 * M1;

  wtall_k<<<dim3(32576), 256, 0, stream>>>(Wq, Wk, Wv, Wo, W1, W2, projW,
                                           Bqkv, Bo, B1t, B2t, Bprj);

  embed_k<<<dim3(2048), 256, 0, stream>>>(x, emb, h);
  for (int i = 0; i < 8; ++i) {
    ln_k<<<dim3(2048), 256, 0, stream>>>(h, ln1g + i * 1024, ln1b + i * 1024, ain);
    gemm8_k<5,1><<<dim3(384), 512, 0, stream>>>(ain, Bqkv + i * M3, nullptr,
                                                qb, nullptr, vtb, 2048, 3072, 1024);
    attn_k<<<dim3(512), 256, 0, stream>>>(qb, kb, vtb, ob);
    gemm8_k<2,2><<<dim3(256), 512, 0, stream>>>(ob, Bo + i * M1, nullptr,
                                                nullptr, h, nullptr, 2048, 1024, 1024);
    ln_k<<<dim3(2048), 256, 0, stream>>>(h, ln2g + i * 1024, ln2b + i * 1024, ain);
    gemm8_k<1,1><<<dim3(512), 512, 0, stream>>>(ain, B1t + i * M4, b1 + i * 4096,
                                                mid, nullptr, nullptr, 2048, 4096, 1024);
    gemm8_k<3,2><<<dim3(256), 512, 0, stream>>>(mid, B2t + i * M4, b2 + i * 1024,
                                                nullptr, h, nullptr, 2048, 1024, 4096);
  }
  ln_k<<<dim3(2048), 256, 0, stream>>>(h, lnfg, lnfb, ain);
  gemm256_k<<<dim3(1000), 1024, 0, stream>>>(ain, Bprj, projb,
                                             (float*)d_out, 2048, 32000, 1024);
}